// Round 2
// baseline (1257.417 us; speedup 1.0000x reference)
//
#include <hip/hip_runtime.h>
#include <hip/hip_bf16.h>
#include <cstdint>

#define HDIM 128

typedef __bf16 bf16x8 __attribute__((ext_vector_type(8)));
typedef unsigned short usx8 __attribute__((ext_vector_type(8)));
typedef float fx4 __attribute__((ext_vector_type(4)));

__device__ __forceinline__ float bf2f(unsigned short u) {
    unsigned int x = ((unsigned int)u) << 16;
    return __uint_as_float(x);
}
__device__ __forceinline__ unsigned short f2bf(float f) {
    unsigned int x = __float_as_uint(f);
    x += 0x7fffu + ((x >> 16) & 1u);
    return (unsigned short)(x >> 16);
}

// ---------------- dtype detection ----------------
// flags[0]=1 if float tensors are bf16 (else fp32); flags[1]=1 if ints are int64
__global__ void detect(const unsigned int* __restrict__ xw,
                       const unsigned int* __restrict__ eiw, int* flags) {
    if (threadIdx.x != 0 || blockIdx.x != 0) return;
    int sane = 0;
    for (int i = 0; i < 64; i++) {
        unsigned int w = xw[i];
        unsigned short s0 = (unsigned short)(w & 0xffffu);
        unsigned short s1 = (unsigned short)(w >> 16);
        unsigned short ss[2] = {s0, s1};
        for (int k = 0; k < 2; k++) {
            int e = (ss[k] >> 7) & 0xFF;
            if ((ss[k] & 0x7fffu) == 0 || (e >= 100 && e <= 140)) sane++;
        }
    }
    flags[0] = (sane >= 110) ? 1 : 0;
    int zeros = 0;
    for (int i = 1; i < 64; i += 2)
        if (eiw[i] == 0) zeros++;
    flags[1] = (zeros >= 24) ? 1 : 0;
}

// ---------------- input conversion to canonical formats ----------------
__global__ void convert_x(const void* __restrict__ xin, unsigned short* __restrict__ xout,
                          const int* __restrict__ flags, int n8) {
    int i = blockIdx.x * blockDim.x + threadIdx.x;
    if (i >= n8) return;
    size_t base = (size_t)i * 8;
    if (flags[0]) {
        *(usx8*)(xout + base) = *((const usx8*)xin + i);
    } else {
        const float* f = (const float*)xin;
        usx8 o;
#pragma unroll
        for (int q = 0; q < 8; q++) o[q] = f2bf(f[base + q]);
        *(usx8*)(xout + base) = o;
    }
}

struct ParamTab {
    const void* p[18];
    int n[18];
    int off[18];
};
__global__ void convert_params(ParamTab t, unsigned short* __restrict__ dst,
                               const int* __restrict__ flags) {
    int b = blockIdx.x;
    const void* src = t.p[b];
    int n = t.n[b];
    unsigned short* o = dst + t.off[b];
    if (flags[0]) {
        const unsigned short* s = (const unsigned short*)src;
        for (int i = threadIdx.x; i < n; i += blockDim.x) o[i] = s[i];
    } else {
        const float* s = (const float*)src;
        for (int i = threadIdx.x; i < n; i += blockDim.x) o[i] = f2bf(s[i]);
    }
}

__global__ void convert_ints(const void* __restrict__ ei, const void* __restrict__ batch,
                             int* __restrict__ ei32, int* __restrict__ b32,
                             const int* __restrict__ flags, int ne2, int n) {
    int i = blockIdx.x * blockDim.x + threadIdx.x;
    if (i >= ne2 + n) return;
    if (flags[1]) {
        if (i < ne2) ei32[i] = (int)((const long long*)ei)[i];
        else b32[i - ne2] = (int)((const long long*)batch)[i - ne2];
    } else {
        if (i < ne2) ei32[i] = ((const int*)ei)[i];
        else b32[i - ne2] = ((const int*)batch)[i - ne2];
    }
}

// ---------------- degree / CSR build ----------------
__global__ void init_deg(float* deg, int n) {
    int i = blockIdx.x * blockDim.x + threadIdx.x;
    if (i < n) deg[i] = 1.0f;  // self-loop
}
__global__ void acc_deg(const int* __restrict__ dst, float* deg, int e) {
    int i = blockIdx.x * blockDim.x + threadIdx.x;
    if (i < e) atomicAdd(&deg[dst[i]], 1.0f);
}
__global__ void finish_deg(const float* __restrict__ deg, float* __restrict__ dis,
                           int* __restrict__ cnt, int n) {
    int i = blockIdx.x * blockDim.x + threadIdx.x;
    if (i < n) {
        float d = deg[i];
        dis[i] = rsqrtf(d);
        cnt[i] = (int)(d - 0.5f);
    }
}
__global__ void scan1(const int* __restrict__ cnt, int* __restrict__ part, int n) {
    __shared__ int ls[256];
    int b = blockIdx.x, t = threadIdx.x;
    int base = b * 1024;
    int s = 0;
    for (int j = t; j < 1024; j += 256) {
        int i = base + j;
        if (i < n) s += cnt[i];
    }
    ls[t] = s;
    __syncthreads();
    for (int o = 128; o > 0; o >>= 1) {
        if (t < o) ls[t] += ls[t + o];
        __syncthreads();
    }
    if (t == 0) part[b] = ls[0];
}
__global__ void scan2(int* part, int nb) {
    __shared__ int ls[128];
    int t = threadIdx.x;
    int orig = (t < nb) ? part[t] : 0;
    ls[t] = orig;
    __syncthreads();
    for (int o = 1; o < 128; o <<= 1) {
        int v = (t >= o) ? ls[t - o] : 0;
        __syncthreads();
        ls[t] += v;
        __syncthreads();
    }
    if (t < nb) part[t] = ls[t] - orig;  // exclusive
}
__global__ void scan3(const int* __restrict__ cnt, const int* __restrict__ part,
                      int* __restrict__ off, int* __restrict__ cursor, int n) {
    __shared__ int ls[256];
    __shared__ int excl[256];
    int b = blockIdx.x, t = threadIdx.x;
    int i0 = b * 1024 + t * 4;
    int c0 = (i0 + 0 < n) ? cnt[i0 + 0] : 0;
    int c1 = (i0 + 1 < n) ? cnt[i0 + 1] : 0;
    int c2 = (i0 + 2 < n) ? cnt[i0 + 2] : 0;
    int c3 = (i0 + 3 < n) ? cnt[i0 + 3] : 0;
    ls[t] = c0 + c1 + c2 + c3;
    __syncthreads();
    if (t == 0) {
        int acc = 0;
        for (int j = 0; j < 256; j++) { excl[j] = acc; acc += ls[j]; }
    }
    __syncthreads();
    int base = part[b] + excl[t];
    if (i0 + 0 < n) { off[i0 + 0] = base; cursor[i0 + 0] = base; base += c0; }
    if (i0 + 1 < n) { off[i0 + 1] = base; cursor[i0 + 1] = base; base += c1; }
    if (i0 + 2 < n) { off[i0 + 2] = base; cursor[i0 + 2] = base; base += c2; }
    if (i0 + 3 < n) { off[i0 + 3] = base; cursor[i0 + 3] = base; }
}
__global__ void fill_csr(const int* __restrict__ src, const int* __restrict__ dst,
                         const float* __restrict__ dis, int* __restrict__ cursor,
                         int* __restrict__ csrc, float* __restrict__ cw, int e) {
    int i = blockIdx.x * blockDim.x + threadIdx.x;
    if (i >= e) return;
    int s = src[i], d = dst[i];
    int pos = atomicAdd(&cursor[d], 1);
    csrc[pos] = s;
    cw[pos] = dis[s] * dis[d];
}

// ---------------- graph boundaries ----------------
__global__ void zero_int(int* p, int n) {
    int i = blockIdx.x * blockDim.x + threadIdx.x;
    if (i < n) p[i] = 0;
}
__global__ void zero_f(float* p, int n) {
    int i = blockIdx.x * blockDim.x + threadIdx.x;
    if (i < n) p[i] = 0.f;
}
__global__ void gcount(const int* __restrict__ batch, int* gcnt, int n) {
    int i = blockIdx.x * blockDim.x + threadIdx.x;
    if (i < n) atomicAdd(&gcnt[batch[i]], 1);
}
__global__ void gscan(const int* __restrict__ gcnt, int* __restrict__ goff, int g) {
    __shared__ int ls[512];
    int t = threadIdx.x;
    int orig = (t < g) ? gcnt[t] : 0;
    ls[t] = orig;
    __syncthreads();
    for (int o = 1; o < 512; o <<= 1) {
        int v = (t >= o) ? ls[t - o] : 0;
        __syncthreads();
        ls[t] += v;
        __syncthreads();
    }
    if (t < g) goff[t] = ls[t] - orig;  // exclusive
}

// ---------------- weight repack to MFMA B-fragment order ----------------
__global__ void repack(const unsigned short* __restrict__ wconv, unsigned short* __restrict__ Wf) {
    int idx = blockIdx.x * blockDim.x + threadIdx.x;
    if (idx >= 3 * 2048) return;
    int layer = idx >> 11;
    int rem = idx & 2047;
    int kt = rem >> 9;
    int nt = (rem >> 6) & 7;
    int lane = rem & 63;
    const unsigned short* W = wconv + layer * HDIM * HDIM;
    int row = lane & 15, quad = lane >> 4;
    unsigned short* o = Wf + ((size_t)layer * 2048 + (size_t)((kt * 8 + nt) * 64 + lane)) * 8;
#pragma unroll
    for (int j = 0; j < 8; j++) {
        int k = kt * 32 + quad * 8 + j;
        o[j] = W[k * HDIM + nt * 16 + row];
    }
}

// ---------------- GEMM: C[M,128] = A[M,128] @ W[128,128], bf16 MFMA ----------------
__global__ __launch_bounds__(256) void mm_mfma(const unsigned short* __restrict__ A,
                                               const unsigned short* __restrict__ Wf,
                                               unsigned short* __restrict__ C, int M) {
    int gid = blockIdx.x * blockDim.x + threadIdx.x;
    int wave = gid >> 6;
    int lane = threadIdx.x & 63;
    int m0 = wave * 16;
    if (m0 >= M) return;
    int row = lane & 15, quad = lane >> 4;
    const unsigned short* arow = A + (size_t)(m0 + row) * HDIM + quad * 8;
    fx4 acc[8];
#pragma unroll
    for (int t = 0; t < 8; t++) acc[t] = (fx4){0.f, 0.f, 0.f, 0.f};
#pragma unroll
    for (int kt = 0; kt < 4; kt++) {
        bf16x8 a = __builtin_bit_cast(bf16x8, *(const usx8*)(arow + kt * 32));
        const unsigned short* wf = Wf + ((size_t)(kt * 8) * 64 + lane) * 8;
#pragma unroll
        for (int nt = 0; nt < 8; nt++) {
            bf16x8 b = __builtin_bit_cast(bf16x8, *(const usx8*)(wf + (size_t)nt * 64 * 8));
            acc[nt] = __builtin_amdgcn_mfma_f32_16x16x32_bf16(a, b, acc[nt], 0, 0, 0);
        }
    }
#pragma unroll
    for (int nt = 0; nt < 8; nt++) {
        int col = nt * 16 + row;
#pragma unroll
        for (int r = 0; r < 4; r++) {
            int m = m0 + quad * 4 + r;
            C[(size_t)m * HDIM + col] = f2bf(acc[nt][r]);
        }
    }
}

// ---------------- aggregation: one wave per node, output bf16 ----------------
__global__ __launch_bounds__(256) void aggregate(const unsigned short* __restrict__ hw,
                                                 const float* __restrict__ dis,
                                                 const int* __restrict__ offs,
                                                 const int* __restrict__ cnt,
                                                 const int* __restrict__ csrc,
                                                 const float* __restrict__ cw,
                                                 const unsigned short* __restrict__ bias,
                                                 unsigned short* __restrict__ agg, int n) {
    int wave = (blockIdx.x * blockDim.x + threadIdx.x) >> 6;
    if (wave >= n) return;
    int lane = threadIdx.x & 63;
    int i = wave;
    float di = dis[i];
    float wl = di * di;
    unsigned int hv = *(const unsigned int*)(hw + (size_t)i * HDIM + lane * 2);
    float a0 = bf2f(bias[lane * 2]) + wl * __uint_as_float(hv << 16);
    float a1 = bf2f(bias[lane * 2 + 1]) + wl * __uint_as_float(hv & 0xffff0000u);
    int o = offs[i], c = cnt[i];
    for (int j = 0; j < c; j++) {
        int s = csrc[o + j];
        float w = cw[o + j];
        unsigned int v = *(const unsigned int*)(hw + (size_t)s * HDIM + lane * 2);
        a0 += w * __uint_as_float(v << 16);
        a1 += w * __uint_as_float(v & 0xffff0000u);
    }
    unsigned int packed = ((unsigned int)f2bf(a1) << 16) | (unsigned int)f2bf(a0);
    ((unsigned int*)agg)[(size_t)i * 64 + lane] = packed;
}

// ---------------- BN stats / finalize / apply ----------------
__global__ void col_stats(const unsigned short* __restrict__ agg, float* __restrict__ gsum,
                          float* __restrict__ gsq, int n) {
    int t = threadIdx.x;
    int c = t & 127, p = t >> 7;
    float s = 0.f, s2 = 0.f;
    int stride = gridDim.x * 2;
    for (int r = blockIdx.x * 2 + p; r < n; r += stride) {
        float v = bf2f(agg[(size_t)r * HDIM + c]);
        s += v;
        s2 += v * v;
    }
    __shared__ float ls[256], ls2[256];
    ls[t] = s;
    ls2[t] = s2;
    __syncthreads();
    if (t < 128) {
        atomicAdd(&gsum[t], ls[t] + ls[t + 128]);
        atomicAdd(&gsq[t], ls2[t] + ls2[t + 128]);
    }
}
__global__ void bn_finalize(const float* __restrict__ gsum, const float* __restrict__ gsq,
                            const unsigned short* __restrict__ g,
                            const unsigned short* __restrict__ be,
                            float* __restrict__ sc, float* __restrict__ sh, float invn) {
    int c = threadIdx.x;
    if (c < 128) {
        float m = gsum[c] * invn;
        float v = gsq[c] * invn - m * m;
        float s = bf2f(g[c]) * rsqrtf(v + 1e-5f);
        sc[c] = s;
        sh[c] = bf2f(be[c]) - m * s;
    }
}
__global__ void bn_relu(unsigned short* __restrict__ agg, const float* __restrict__ sc,
                        const float* __restrict__ sh, int nthreads) {
    int idx = blockIdx.x * blockDim.x + threadIdx.x;
    if (idx >= nthreads) return;
    size_t base = (size_t)idx * 8;
    int c0 = (int)(base & 127);
    usx8 v = *(usx8*)(agg + base);
    usx8 o;
#pragma unroll
    for (int q = 0; q < 8; q++)
        o[q] = f2bf(fmaxf(sc[c0 + q] * bf2f(v[q]) + sh[c0 + q], 0.f));
    *(usx8*)(agg + base) = o;
}

// ---------------- pooling + head ----------------
__global__ void pool(const unsigned short* __restrict__ hin, const int* __restrict__ goff,
                     const int* __restrict__ gcnt, float* __restrict__ pooled) {
    int g = blockIdx.x, t = threadIdx.x;
    int c = t & 127, p = t >> 7;
    int s = goff[g], cn = gcnt[g];
    float acc = 0.f;
    for (int r = s + p; r < s + cn; r += 2) acc += bf2f(hin[(size_t)r * HDIM + c]);
    __shared__ float ls[256];
    ls[t] = acc;
    __syncthreads();
    if (t < 128) pooled[(size_t)g * HDIM + t] = (ls[t] + ls[t + 128]) / fmaxf((float)cn, 1.f);
}
__global__ void pooled_bn(const float* __restrict__ pooled, const unsigned short* __restrict__ g,
                          const unsigned short* __restrict__ be, float* __restrict__ psc,
                          float* __restrict__ psh, int G_) {
    int t = threadIdx.x;
    int c = t & 127, p = t >> 7;
    float s = 0.f, s2 = 0.f;
    for (int r = p; r < G_; r += 4) {
        float v = pooled[(size_t)r * HDIM + c];
        s += v;
        s2 += v * v;
    }
    __shared__ float ls[512], ls2[512];
    ls[t] = s;
    ls2[t] = s2;
    __syncthreads();
    if (t < 128) {
        float S = ls[t] + ls[t + 128] + ls[t + 256] + ls[t + 384];
        float S2 = ls2[t] + ls2[t + 128] + ls2[t + 256] + ls2[t + 384];
        float m = S / (float)G_;
        float v = S2 / (float)G_ - m * m;
        float sc = bf2f(g[t]) * rsqrtf(v + 1e-5f);
        psc[t] = sc;
        psh[t] = bf2f(be[t]) - m * sc;
    }
}
__global__ void mlp1(const float* __restrict__ pooled, const float* __restrict__ psc,
                     const float* __restrict__ psh, const unsigned short* __restrict__ lw1,
                     const unsigned short* __restrict__ lb1, float* __restrict__ z1) {
    int r = blockIdx.x, t = threadIdx.x;
    __shared__ float row[128];
    row[t] = psc[t] * pooled[(size_t)r * HDIM + t] + psh[t];
    __syncthreads();
    float acc = bf2f(lb1[t]);
    for (int k = 0; k < 128; k++) acc += row[k] * bf2f(lw1[k * HDIM + t]);
    z1[(size_t)r * HDIM + t] = fmaxf(acc, 0.f);
}
__global__ void mlp2(const float* __restrict__ z1, const unsigned short* __restrict__ lw2,
                     const unsigned short* __restrict__ lb2, void* __restrict__ out,
                     const int* __restrict__ flags) {
    int r = blockIdx.x, t = threadIdx.x;
    __shared__ float row[128];
    __shared__ float z2[10];
    __shared__ float lse;
    row[t] = z1[(size_t)r * HDIM + t];
    __syncthreads();
    if (t < 10) {
        float a = bf2f(lb2[t]);
        for (int k = 0; k < 128; k++) a += row[k] * bf2f(lw2[k * 10 + t]);
        z2[t] = a;
    }
    __syncthreads();
    if (t == 0) {
        float m = z2[0];
        for (int j = 1; j < 10; j++) m = fmaxf(m, z2[j]);
        float s = 0.f;
        for (int j = 0; j < 10; j++) s += expf(z2[j] - m);
        lse = m + logf(s);
    }
    __syncthreads();
    if (t < 10) {
        float v = z2[t] - lse;
        if (flags[0]) ((unsigned short*)out)[r * 10 + t] = f2bf(v);
        else ((float*)out)[r * 10 + t] = v;
    }
}

extern "C" void kernel_launch(void* const* d_in, const int* in_sizes, int n_in,
                              void* d_out, int out_size, void* d_ws, size_t ws_size,
                              hipStream_t stream) {
    const void* x = d_in[0];
    const void* ei = d_in[1];
    const void* batch = d_in[2];

    int N_ = in_sizes[2];
    int E_ = in_sizes[1] / 2;
    int G_ = out_size / 10;

    char* ws = (char*)d_ws;
    auto alloc = [&](size_t bytes) -> char* {
        char* p = ws;
        ws += (bytes + 255) & ~(size_t)255;
        return p;
    };
    int* flags = (int*)alloc(256);
    float* dis = (float*)alloc((size_t)N_ * 4);
    float* degf = (float*)alloc((size_t)N_ * 4);
    int* cnt = (int*)alloc((size_t)N_ * 4);
    int* offs = (int*)alloc((size_t)N_ * 4);
    int* cursor = (int*)alloc((size_t)N_ * 4);
    int* part = (int*)alloc(4096);
    int* csrc = (int*)alloc((size_t)E_ * 4);
    float* cw = (float*)alloc((size_t)E_ * 4);
    // overlay region: [ei32 (2E ints) | batch32 (N ints)] reused later as hw (N*128 bf16)
    size_t ovl = ((size_t)2 * E_ * 4 + (size_t)N_ * 4 + 512);
    size_t hw_bytes = (size_t)N_ * HDIM * 2;
    if (hw_bytes > ovl) ovl = hw_bytes;
    char* ovl_base = alloc(ovl);
    int* ei32 = (int*)ovl_base;
    int* b32 = (int*)(ovl_base + ((size_t)2 * E_ * 4 + 255 & ~(size_t)255));
    unsigned short* hw = (unsigned short*)ovl_base;
    // aggbuf: doubles as converted-x, agg output, and hin (bf16 N*128)
    unsigned short* aggbuf = (unsigned short*)alloc((size_t)N_ * HDIM * 2);
    unsigned short* wconv = (unsigned short*)alloc(70000 * 2);
    unsigned short* wfrag = (unsigned short*)alloc(3 * HDIM * HDIM * 2);
    float* gsum = (float*)alloc(256 * 4);
    float* gsq = gsum + 128;
    float* bsc = (float*)alloc(128 * 4);
    float* bsh = (float*)alloc(128 * 4);
    int* gcnt = (int*)alloc((size_t)G_ * 4);
    int* goff = (int*)alloc((size_t)G_ * 4);
    float* pooled = (float*)alloc((size_t)G_ * HDIM * 4);
    float* psc = (float*)alloc(128 * 4);
    float* psh = (float*)alloc(128 * 4);
    float* z1 = (float*)alloc((size_t)G_ * HDIM * 4);

    // wconv layout (element offsets)
    const int oW = 0;                 // W1,W2,W3: 3*16384
    const int oB = 49152;             // b,g,be per layer (384 each), then gp,bep
    const int oLB1 = oB + 1408;       // 50560
    const int oLW1 = oLB1 + 128;      // 50688
    const int oLW2 = oLW1 + 16384;    // 67072
    const int oLB2 = oLW2 + 1280;     // 68352

    detect<<<1, 64, 0, stream>>>((const unsigned int*)x, (const unsigned int*)ei, flags);

    int n8 = N_ * HDIM / 8;
    convert_x<<<(n8 + 255) / 256, 256, 0, stream>>>(x, aggbuf, flags, n8);

    ParamTab tab;
    const int srcIdx[18] = {3, 7, 11, 4, 5, 6, 8, 9, 10, 12, 13, 14, 15, 16, 18, 17, 19, 20};
    const int dstOff[18] = {oW, oW + 16384, oW + 32768,
                            oB + 0, oB + 128, oB + 256,
                            oB + 384, oB + 512, oB + 640,
                            oB + 768, oB + 896, oB + 1024,
                            oB + 1152, oB + 1280,
                            oLB1, oLW1, oLW2, oLB2};
    for (int i = 0; i < 18; i++) {
        tab.p[i] = d_in[srcIdx[i]];
        tab.n[i] = in_sizes[srcIdx[i]];
        tab.off[i] = dstOff[i];
    }
    convert_params<<<18, 256, 0, stream>>>(tab, wconv, flags);

    convert_ints<<<(2 * E_ + N_ + 255) / 256, 256, 0, stream>>>(ei, batch, ei32, b32, flags,
                                                                2 * E_, N_);
    const int* src32 = ei32;
    const int* dst32 = ei32 + E_;

    int nb256 = (N_ + 255) / 256;
    int eb256 = (E_ + 255) / 256;
    int nblk = (N_ + 1023) / 1024;

    init_deg<<<nb256, 256, 0, stream>>>(degf, N_);
    acc_deg<<<eb256, 256, 0, stream>>>(dst32, degf, E_);
    finish_deg<<<nb256, 256, 0, stream>>>(degf, dis, cnt, N_);
    scan1<<<nblk, 256, 0, stream>>>(cnt, part, N_);
    scan2<<<1, 128, 0, stream>>>(part, nblk);
    scan3<<<nblk, 256, 0, stream>>>(cnt, part, offs, cursor, N_);
    fill_csr<<<eb256, 256, 0, stream>>>(src32, dst32, dis, cursor, csrc, cw, E_);

    zero_int<<<(G_ + 255) / 256, 256, 0, stream>>>(gcnt, G_);
    gcount<<<nb256, 256, 0, stream>>>(b32, gcnt, N_);
    gscan<<<1, 512, 0, stream>>>(gcnt, goff, G_);

    repack<<<(3 * 2048 + 255) / 256, 256, 0, stream>>>(wconv, wfrag);

    int mm_blocks = (((N_ + 15) / 16) * 64 + 255) / 256;
    int agg_blocks = (int)(((size_t)N_ * 64 + 255) / 256);
    int ap_blocks = (n8 + 255) / 256;
    float invn = 1.f / (float)N_;

    for (int l = 0; l < 3; l++) {
        mm_mfma<<<mm_blocks, 256, 0, stream>>>(aggbuf, wfrag + (size_t)l * HDIM * HDIM, hw, N_);
        aggregate<<<agg_blocks, 256, 0, stream>>>(hw, dis, offs, cnt, csrc, cw,
                                                  wconv + oB + l * 384, aggbuf, N_);
        zero_f<<<1, 256, 0, stream>>>(gsum, 256);
        col_stats<<<256, 256, 0, stream>>>(aggbuf, gsum, gsq, N_);
        bn_finalize<<<1, 128, 0, stream>>>(gsum, gsq, wconv + oB + l * 384 + 128,
                                           wconv + oB + l * 384 + 256, bsc, bsh, invn);
        bn_relu<<<ap_blocks, 256, 0, stream>>>(aggbuf, bsc, bsh, n8);
    }

    pool<<<G_, 256, 0, stream>>>(aggbuf, goff, gcnt, pooled);
    pooled_bn<<<1, 512, 0, stream>>>(pooled, wconv + oB + 1152, wconv + oB + 1280, psc, psh, G_);
    mlp1<<<G_, 128, 0, stream>>>(pooled, psc, psh, wconv + oLW1, wconv + oLB1, z1);
    mlp2<<<G_, 128, 0, stream>>>(z1, wconv + oLW2, wconv + oLB2, d_out, flags);
}

// Round 3
// 890.168 us; speedup vs baseline: 1.4126x; 1.4126x over previous
//
#include <hip/hip_runtime.h>
#include <hip/hip_bf16.h>
#include <cstdint>

#define HDIM 128

typedef __bf16 bf16x8 __attribute__((ext_vector_type(8)));
typedef unsigned short usx8 __attribute__((ext_vector_type(8)));
typedef float fx4 __attribute__((ext_vector_type(4)));

__device__ __forceinline__ float bf2f(unsigned short u) {
    unsigned int x = ((unsigned int)u) << 16;
    return __uint_as_float(x);
}
__device__ __forceinline__ unsigned short f2bf(float f) {
    unsigned int x = __float_as_uint(f);
    x += 0x7fffu + ((x >> 16) & 1u);
    return (unsigned short)(x >> 16);
}

// ---------------- dtype detection ----------------
// flags[0]=1 if float tensors are bf16 (else fp32); flags[1]=1 if ints are int64
__global__ void detect(const unsigned int* __restrict__ xw,
                       const unsigned int* __restrict__ eiw, int* flags) {
    if (threadIdx.x != 0 || blockIdx.x != 0) return;
    int sane = 0;
    for (int i = 0; i < 64; i++) {
        unsigned int w = xw[i];
        unsigned short s0 = (unsigned short)(w & 0xffffu);
        unsigned short s1 = (unsigned short)(w >> 16);
        unsigned short ss[2] = {s0, s1};
        for (int k = 0; k < 2; k++) {
            int e = (ss[k] >> 7) & 0xFF;
            if ((ss[k] & 0x7fffu) == 0 || (e >= 100 && e <= 140)) sane++;
        }
    }
    flags[0] = (sane >= 110) ? 1 : 0;
    int zeros = 0;
    for (int i = 1; i < 64; i += 2)
        if (eiw[i] == 0) zeros++;
    flags[1] = (zeros >= 24) ? 1 : 0;
}

// ---------------- input conversion ----------------
__global__ void convert_x(const void* __restrict__ xin, unsigned short* __restrict__ xout,
                          const int* __restrict__ flags, int n8) {
    int i = blockIdx.x * blockDim.x + threadIdx.x;
    if (i >= n8) return;
    size_t base = (size_t)i * 8;
    if (flags[0]) {
        *(usx8*)(xout + base) = *((const usx8*)xin + i);
    } else {
        const float* f = (const float*)xin;
        usx8 o;
#pragma unroll
        for (int q = 0; q < 8; q++) o[q] = f2bf(f[base + q]);
        *(usx8*)(xout + base) = o;
    }
}

struct ParamTab {
    const void* p[18];
    int n[18];
    int off[18];
};
__global__ void convert_params(ParamTab t, unsigned short* __restrict__ dst,
                               const int* __restrict__ flags) {
    int b = blockIdx.x;
    const void* src = t.p[b];
    int n = t.n[b];
    unsigned short* o = dst + t.off[b];
    if (flags[0]) {
        const unsigned short* s = (const unsigned short*)src;
        for (int i = threadIdx.x; i < n; i += blockDim.x) o[i] = s[i];
    } else {
        const float* s = (const float*)src;
        for (int i = threadIdx.x; i < n; i += blockDim.x) o[i] = f2bf(s[i]);
    }
}

// ---------------- init ----------------
__global__ void init_all(float* __restrict__ degf, int* __restrict__ gcnt,
                         float* __restrict__ gsumAll, int n, int g) {
    int i = blockIdx.x * blockDim.x + threadIdx.x;
    if (i < n) degf[i] = 1.0f;  // self-loop
    if (i < g) gcnt[i] = 0;
    if (i < 768) gsumAll[i] = 0.f;
}

// ---------------- degree / CSR build (reads raw edge_index via flag) ----------------
__global__ void acc_deg(const void* __restrict__ ei, float* deg,
                        const int* __restrict__ flags, int e) {
    int i = blockIdx.x * blockDim.x + threadIdx.x;
    if (i >= e) return;
    int d = flags[1] ? (int)((const long long*)ei)[e + i] : ((const int*)ei)[e + i];
    atomicAdd(&deg[d], 1.0f);
}
__global__ void finish_deg(const float* __restrict__ deg, float* __restrict__ dis,
                           int* __restrict__ cnt, int n) {
    int i = blockIdx.x * blockDim.x + threadIdx.x;
    if (i < n) {
        float d = deg[i];
        dis[i] = rsqrtf(d);
        cnt[i] = (int)(d - 0.5f);
    }
}
__global__ void scan1(const int* __restrict__ cnt, int* __restrict__ part, int n) {
    __shared__ int ls[256];
    int b = blockIdx.x, t = threadIdx.x;
    int base = b * 1024;
    int s = 0;
    for (int j = t; j < 1024; j += 256) {
        int i = base + j;
        if (i < n) s += cnt[i];
    }
    ls[t] = s;
    __syncthreads();
    for (int o = 128; o > 0; o >>= 1) {
        if (t < o) ls[t] += ls[t + o];
        __syncthreads();
    }
    if (t == 0) part[b] = ls[0];
}
__global__ void scan2(int* part, int nb) {
    __shared__ int ls[128];
    int t = threadIdx.x;
    int orig = (t < nb) ? part[t] : 0;
    ls[t] = orig;
    __syncthreads();
    for (int o = 1; o < 128; o <<= 1) {
        int v = (t >= o) ? ls[t - o] : 0;
        __syncthreads();
        ls[t] += v;
        __syncthreads();
    }
    if (t < nb) part[t] = ls[t] - orig;  // exclusive
}
__global__ void scan3(const int* __restrict__ cnt, const int* __restrict__ part,
                      int* __restrict__ off, int* __restrict__ cursor, int n) {
    __shared__ int ls[256];
    __shared__ int excl[256];
    int b = blockIdx.x, t = threadIdx.x;
    int i0 = b * 1024 + t * 4;
    int c0 = (i0 + 0 < n) ? cnt[i0 + 0] : 0;
    int c1 = (i0 + 1 < n) ? cnt[i0 + 1] : 0;
    int c2 = (i0 + 2 < n) ? cnt[i0 + 2] : 0;
    int c3 = (i0 + 3 < n) ? cnt[i0 + 3] : 0;
    ls[t] = c0 + c1 + c2 + c3;
    __syncthreads();
    if (t == 0) {
        int acc = 0;
        for (int j = 0; j < 256; j++) { excl[j] = acc; acc += ls[j]; }
    }
    __syncthreads();
    int base = part[b] + excl[t];
    if (i0 + 0 < n) { off[i0 + 0] = base; cursor[i0 + 0] = base; base += c0; }
    if (i0 + 1 < n) { off[i0 + 1] = base; cursor[i0 + 1] = base; base += c1; }
    if (i0 + 2 < n) { off[i0 + 2] = base; cursor[i0 + 2] = base; base += c2; }
    if (i0 + 3 < n) { off[i0 + 3] = base; cursor[i0 + 3] = base; }
}
__global__ void fill_csr(const void* __restrict__ ei, const float* __restrict__ dis,
                         int* __restrict__ cursor, int* __restrict__ csrc,
                         float* __restrict__ cw, const int* __restrict__ flags, int e) {
    int i = blockIdx.x * blockDim.x + threadIdx.x;
    if (i >= e) return;
    int s, d;
    if (flags[1]) {
        s = (int)((const long long*)ei)[i];
        d = (int)((const long long*)ei)[e + i];
    } else {
        s = ((const int*)ei)[i];
        d = ((const int*)ei)[e + i];
    }
    int pos = atomicAdd(&cursor[d], 1);
    csrc[pos] = s;
    cw[pos] = dis[s] * dis[d];
}

// ---------------- graph boundaries ----------------
__global__ void gcount(const void* __restrict__ batch, int* gcnt,
                       const int* __restrict__ flags, int n) {
    int i = blockIdx.x * blockDim.x + threadIdx.x;
    if (i >= n) return;
    int b = flags[1] ? (int)((const long long*)batch)[i] : ((const int*)batch)[i];
    atomicAdd(&gcnt[b], 1);
}
__global__ void gscan(const int* __restrict__ gcnt, int* __restrict__ goff, int g) {
    __shared__ int ls[512];
    int t = threadIdx.x;
    int orig = (t < g) ? gcnt[t] : 0;
    ls[t] = orig;
    __syncthreads();
    for (int o = 1; o < 512; o <<= 1) {
        int v = (t >= o) ? ls[t - o] : 0;
        __syncthreads();
        ls[t] += v;
        __syncthreads();
    }
    if (t < g) goff[t] = ls[t] - orig;  // exclusive
}

// ---------------- weight repack to MFMA B-fragment order ----------------
__global__ void repack(const unsigned short* __restrict__ wconv, unsigned short* __restrict__ Wf) {
    int idx = blockIdx.x * blockDim.x + threadIdx.x;
    if (idx >= 3 * 2048) return;
    int layer = idx >> 11;
    int rem = idx & 2047;
    int kt = rem >> 9;
    int nt = (rem >> 6) & 7;
    int lane = rem & 63;
    const unsigned short* W = wconv + layer * HDIM * HDIM;
    int row = lane & 15, quad = lane >> 4;
    unsigned short* o = Wf + ((size_t)layer * 2048 + (size_t)((kt * 8 + nt) * 64 + lane)) * 8;
#pragma unroll
    for (int j = 0; j < 8; j++) {
        int k = kt * 32 + quad * 8 + j;
        o[j] = W[k * HDIM + nt * 16 + row];
    }
}

// ---------------- GEMM: C[M,128] = relu(sc*A+sh) @ W, bf16 MFMA ----------------
__global__ __launch_bounds__(256) void mm_mfma(const unsigned short* __restrict__ A,
                                               const unsigned short* __restrict__ Wf,
                                               unsigned short* __restrict__ C, int M,
                                               const float* __restrict__ sc,
                                               const float* __restrict__ sh) {
    int gid = blockIdx.x * blockDim.x + threadIdx.x;
    int wave = gid >> 6;
    int lane = threadIdx.x & 63;
    int m0 = wave * 16;
    if (m0 >= M) return;
    int row = lane & 15, quad = lane >> 4;
    const unsigned short* arow = A + (size_t)(m0 + row) * HDIM + quad * 8;
    fx4 acc[8];
#pragma unroll
    for (int t = 0; t < 8; t++) acc[t] = (fx4){0.f, 0.f, 0.f, 0.f};
#pragma unroll
    for (int kt = 0; kt < 4; kt++) {
        usx8 raw = *(const usx8*)(arow + kt * 32);
        bf16x8 a;
        if (sc) {
            int col = kt * 32 + quad * 8;
            fx4 s0 = *(const fx4*)(sc + col);
            fx4 s1 = *(const fx4*)(sc + col + 4);
            fx4 h0 = *(const fx4*)(sh + col);
            fx4 h1 = *(const fx4*)(sh + col + 4);
            usx8 t;
#pragma unroll
            for (int q = 0; q < 4; q++) t[q] = f2bf(fmaxf(s0[q] * bf2f(raw[q]) + h0[q], 0.f));
#pragma unroll
            for (int q = 0; q < 4; q++)
                t[4 + q] = f2bf(fmaxf(s1[q] * bf2f(raw[4 + q]) + h1[q], 0.f));
            a = __builtin_bit_cast(bf16x8, t);
        } else {
            a = __builtin_bit_cast(bf16x8, raw);
        }
        const unsigned short* wf = Wf + ((size_t)(kt * 8) * 64 + lane) * 8;
#pragma unroll
        for (int nt = 0; nt < 8; nt++) {
            bf16x8 b = __builtin_bit_cast(bf16x8, *(const usx8*)(wf + (size_t)nt * 64 * 8));
            acc[nt] = __builtin_amdgcn_mfma_f32_16x16x32_bf16(a, b, acc[nt], 0, 0, 0);
        }
    }
#pragma unroll
    for (int nt = 0; nt < 8; nt++) {
        int col = nt * 16 + row;
#pragma unroll
        for (int r = 0; r < 4; r++) {
            int m = m0 + quad * 4 + r;
            C[(size_t)m * HDIM + col] = f2bf(acc[nt][r]);
        }
    }
}

// ---------------- aggregation: 4 nodes/wave, 16B gathers, idx prefetch ----------------
__global__ __launch_bounds__(256) void aggregate(const unsigned short* __restrict__ hw,
                                                 const float* __restrict__ dis,
                                                 const int* __restrict__ offs,
                                                 const int* __restrict__ cnt,
                                                 const int* __restrict__ csrc,
                                                 const float* __restrict__ cw,
                                                 const unsigned short* __restrict__ bias,
                                                 unsigned short* __restrict__ agg, int n) {
    int wv = (blockIdx.x * blockDim.x + threadIdx.x) >> 6;
    int lane = threadIdx.x & 63;
    int grp = lane >> 4, sub = lane & 15;
    int node = wv * 4 + grp;
    if (node >= n) return;
    int colb = sub * 8;
    usx8 bv = *(const usx8*)(bias + colb);
    float di = dis[node];
    float wl = di * di;
    usx8 sv = *(const usx8*)(hw + (size_t)node * HDIM + colb);
    float a[8];
#pragma unroll
    for (int q = 0; q < 8; q++) a[q] = bf2f(bv[q]) + wl * bf2f(sv[q]);
    int o = offs[node], c = cnt[node];
    int s0 = 0, s1 = 0;
    float w0 = 0.f, w1 = 0.f;
    if (c > 0) { s0 = csrc[o]; w0 = cw[o]; }
    if (c > 1) { s1 = csrc[o + 1]; w1 = cw[o + 1]; }
    for (int j = 0; j < c; j++) {
        usx8 v = *(const usx8*)(hw + (size_t)s0 * HDIM + colb);
        int s2 = 0;
        float w2 = 0.f;
        if (j + 2 < c) { s2 = csrc[o + j + 2]; w2 = cw[o + j + 2]; }
#pragma unroll
        for (int q = 0; q < 8; q++) a[q] += w0 * bf2f(v[q]);
        s0 = s1; w0 = w1;
        s1 = s2; w1 = w2;
    }
    usx8 ov;
#pragma unroll
    for (int q = 0; q < 8; q++) ov[q] = f2bf(a[q]);
    *(usx8*)(agg + (size_t)node * HDIM + colb) = ov;
}

// ---------------- BN stats / finalize ----------------
__global__ void col_stats(const unsigned short* __restrict__ agg, float* __restrict__ gsum,
                          float* __restrict__ gsq, int n) {
    int t = threadIdx.x;
    int c = t & 127, p = t >> 7;
    float s = 0.f, s2 = 0.f;
    int stride = gridDim.x * 2;
    for (int r = blockIdx.x * 2 + p; r < n; r += stride) {
        float v = bf2f(agg[(size_t)r * HDIM + c]);
        s += v;
        s2 += v * v;
    }
    __shared__ float ls[256], ls2[256];
    ls[t] = s;
    ls2[t] = s2;
    __syncthreads();
    if (t < 128) {
        atomicAdd(&gsum[t], ls[t] + ls[t + 128]);
        atomicAdd(&gsq[t], ls2[t] + ls2[t + 128]);
    }
}
__global__ void bn_finalize(const float* __restrict__ gsum, const float* __restrict__ gsq,
                            const unsigned short* __restrict__ g,
                            const unsigned short* __restrict__ be,
                            float* __restrict__ sc, float* __restrict__ sh, float invn) {
    int c = threadIdx.x;
    if (c < 128) {
        float m = gsum[c] * invn;
        float v = gsq[c] * invn - m * m;
        float s = bf2f(g[c]) * rsqrtf(v + 1e-5f);
        sc[c] = s;
        sh[c] = bf2f(be[c]) - m * s;
    }
}

// ---------------- pooling (fused BN3+ReLU) + head ----------------
__global__ void pool(const unsigned short* __restrict__ hin, const int* __restrict__ goff,
                     const int* __restrict__ gcnt, const float* __restrict__ sc,
                     const float* __restrict__ sh, float* __restrict__ pooled) {
    int g = blockIdx.x, t = threadIdx.x;
    int c = t & 127, p = t >> 7;
    float scale = sc[c], shift = sh[c];
    int s = goff[g], cn = gcnt[g];
    float acc = 0.f;
    for (int r = s + p; r < s + cn; r += 2)
        acc += fmaxf(scale * bf2f(hin[(size_t)r * HDIM + c]) + shift, 0.f);
    __shared__ float ls[256];
    ls[t] = acc;
    __syncthreads();
    if (t < 128) pooled[(size_t)g * HDIM + t] = (ls[t] + ls[t + 128]) / fmaxf((float)cn, 1.f);
}
__global__ void pooled_bn(const float* __restrict__ pooled, const unsigned short* __restrict__ g,
                          const unsigned short* __restrict__ be, float* __restrict__ psc,
                          float* __restrict__ psh, int G_) {
    int t = threadIdx.x;
    int c = t & 127, p = t >> 7;
    float s = 0.f, s2 = 0.f;
    for (int r = p; r < G_; r += 4) {
        float v = pooled[(size_t)r * HDIM + c];
        s += v;
        s2 += v * v;
    }
    __shared__ float ls[512], ls2[512];
    ls[t] = s;
    ls2[t] = s2;
    __syncthreads();
    if (t < 128) {
        float S = ls[t] + ls[t + 128] + ls[t + 256] + ls[t + 384];
        float S2 = ls2[t] + ls2[t + 128] + ls2[t + 256] + ls2[t + 384];
        float m = S / (float)G_;
        float v = S2 / (float)G_ - m * m;
        float sc = bf2f(g[t]) * rsqrtf(v + 1e-5f);
        psc[t] = sc;
        psh[t] = bf2f(be[t]) - m * sc;
    }
}
__global__ void mlp1(const float* __restrict__ pooled, const float* __restrict__ psc,
                     const float* __restrict__ psh, const unsigned short* __restrict__ lw1,
                     const unsigned short* __restrict__ lb1, float* __restrict__ z1) {
    int r = blockIdx.x, t = threadIdx.x;
    __shared__ float row[128];
    row[t] = psc[t] * pooled[(size_t)r * HDIM + t] + psh[t];
    __syncthreads();
    float acc = bf2f(lb1[t]);
    for (int k = 0; k < 128; k++) acc += row[k] * bf2f(lw1[k * HDIM + t]);
    z1[(size_t)r * HDIM + t] = fmaxf(acc, 0.f);
}
__global__ void mlp2(const float* __restrict__ z1, const unsigned short* __restrict__ lw2,
                     const unsigned short* __restrict__ lb2, void* __restrict__ out,
                     const int* __restrict__ flags) {
    int r = blockIdx.x, t = threadIdx.x;
    __shared__ float row[128];
    __shared__ float z2[10];
    __shared__ float lse;
    row[t] = z1[(size_t)r * HDIM + t];
    __syncthreads();
    if (t < 10) {
        float a = bf2f(lb2[t]);
        for (int k = 0; k < 128; k++) a += row[k] * bf2f(lw2[k * 10 + t]);
        z2[t] = a;
    }
    __syncthreads();
    if (t == 0) {
        float m = z2[0];
        for (int j = 1; j < 10; j++) m = fmaxf(m, z2[j]);
        float s = 0.f;
        for (int j = 0; j < 10; j++) s += expf(z2[j] - m);
        lse = m + logf(s);
    }
    __syncthreads();
    if (t < 10) {
        float v = z2[t] - lse;
        if (flags[0]) ((unsigned short*)out)[r * 10 + t] = f2bf(v);
        else ((float*)out)[r * 10 + t] = v;
    }
}

extern "C" void kernel_launch(void* const* d_in, const int* in_sizes, int n_in,
                              void* d_out, int out_size, void* d_ws, size_t ws_size,
                              hipStream_t stream) {
    const void* x = d_in[0];
    const void* ei = d_in[1];
    const void* batch = d_in[2];

    int N_ = in_sizes[2];
    int E_ = in_sizes[1] / 2;
    int G_ = out_size / 10;

    char* ws = (char*)d_ws;
    auto alloc = [&](size_t bytes) -> char* {
        char* p = ws;
        ws += (bytes + 255) & ~(size_t)255;
        return p;
    };
    int* flags = (int*)alloc(256);
    float* dis = (float*)alloc((size_t)N_ * 4);
    float* degf = (float*)alloc((size_t)N_ * 4);
    int* cnt = (int*)alloc((size_t)N_ * 4);
    int* offs = (int*)alloc((size_t)N_ * 4);
    int* cursor = (int*)alloc((size_t)N_ * 4);
    int* part = (int*)alloc(4096);
    int* csrc = (int*)alloc((size_t)E_ * 4);
    float* cw = (float*)alloc((size_t)E_ * 4);
    unsigned short* hw = (unsigned short*)alloc((size_t)N_ * HDIM * 2);
    unsigned short* aggbuf = (unsigned short*)alloc((size_t)N_ * HDIM * 2);
    unsigned short* wconv = (unsigned short*)alloc(70000 * 2);
    unsigned short* wfrag = (unsigned short*)alloc(3 * HDIM * HDIM * 2);
    float* gsumAll = (float*)alloc(768 * 4);  // per-layer: gsum[128]+gsq[128]
    float* bsc = (float*)alloc(128 * 4);
    float* bsh = (float*)alloc(128 * 4);
    int* gcnt = (int*)alloc((size_t)G_ * 4);
    int* goff = (int*)alloc((size_t)G_ * 4);
    float* pooled = (float*)alloc((size_t)G_ * HDIM * 4);
    float* psc = (float*)alloc(128 * 4);
    float* psh = (float*)alloc(128 * 4);
    float* z1 = (float*)alloc((size_t)G_ * HDIM * 4);

    // wconv layout (element offsets)
    const int oW = 0;
    const int oB = 49152;
    const int oLB1 = oB + 1408;
    const int oLW1 = oLB1 + 128;
    const int oLW2 = oLW1 + 16384;
    const int oLB2 = oLW2 + 1280;

    detect<<<1, 64, 0, stream>>>((const unsigned int*)x, (const unsigned int*)ei, flags);

    int n8 = N_ * HDIM / 8;
    convert_x<<<(n8 + 255) / 256, 256, 0, stream>>>(x, aggbuf, flags, n8);

    ParamTab tab;
    const int srcIdx[18] = {3, 7, 11, 4, 5, 6, 8, 9, 10, 12, 13, 14, 15, 16, 18, 17, 19, 20};
    const int dstOff[18] = {oW, oW + 16384, oW + 32768,
                            oB + 0, oB + 128, oB + 256,
                            oB + 384, oB + 512, oB + 640,
                            oB + 768, oB + 896, oB + 1024,
                            oB + 1152, oB + 1280,
                            oLB1, oLW1, oLW2, oLB2};
    for (int i = 0; i < 18; i++) {
        tab.p[i] = d_in[srcIdx[i]];
        tab.n[i] = in_sizes[srcIdx[i]];
        tab.off[i] = dstOff[i];
    }
    convert_params<<<18, 256, 0, stream>>>(tab, wconv, flags);

    int nb256 = (N_ + 255) / 256;
    int eb256 = (E_ + 255) / 256;
    int nblk = (N_ + 1023) / 1024;

    init_all<<<nb256, 256, 0, stream>>>(degf, gcnt, gsumAll, N_, G_);
    acc_deg<<<eb256, 256, 0, stream>>>(ei, degf, flags, E_);
    finish_deg<<<nb256, 256, 0, stream>>>(degf, dis, cnt, N_);
    scan1<<<nblk, 256, 0, stream>>>(cnt, part, N_);
    scan2<<<1, 128, 0, stream>>>(part, nblk);
    scan3<<<nblk, 256, 0, stream>>>(cnt, part, offs, cursor, N_);
    fill_csr<<<eb256, 256, 0, stream>>>(ei, dis, cursor, csrc, cw, flags, E_);

    gcount<<<nb256, 256, 0, stream>>>(batch, gcnt, flags, N_);
    gscan<<<1, 512, 0, stream>>>(gcnt, goff, G_);

    repack<<<(3 * 2048 + 255) / 256, 256, 0, stream>>>(wconv, wfrag);

    int mm_blocks = (((N_ + 15) / 16) * 64 + 255) / 256;
    int agg_blocks = (N_ + 15) / 16;  // 4 nodes/wave, 4 waves/block
    float invn = 1.f / (float)N_;

    for (int l = 0; l < 3; l++) {
        const float* msc = (l == 0) ? nullptr : bsc;
        const float* msh = (l == 0) ? nullptr : bsh;
        mm_mfma<<<mm_blocks, 256, 0, stream>>>(aggbuf, wfrag + (size_t)l * HDIM * HDIM, hw, N_,
                                               msc, msh);
        aggregate<<<agg_blocks, 256, 0, stream>>>(hw, dis, offs, cnt, csrc, cw,
                                                  wconv + oB + l * 384, aggbuf, N_);
        float* gsum = gsumAll + l * 256;
        col_stats<<<512, 256, 0, stream>>>(aggbuf, gsum, gsum + 128, N_);
        bn_finalize<<<1, 128, 0, stream>>>(gsum, gsum + 128, wconv + oB + l * 384 + 128,
                                           wconv + oB + l * 384 + 256, bsc, bsh, invn);
    }

    pool<<<G_, 256, 0, stream>>>(aggbuf, goff, gcnt, bsc, bsh, pooled);
    pooled_bn<<<1, 512, 0, stream>>>(pooled, wconv + oB + 1152, wconv + oB + 1280, psc, psh, G_);
    mlp1<<<G_, 128, 0, stream>>>(pooled, psc, psh, wconv + oLW1, wconv + oLB1, z1);
    mlp2<<<G_, 128, 0, stream>>>(z1, wconv + oLW2, wconv + oLB2, d_out, flags);
}

// Round 4
// 703.173 us; speedup vs baseline: 1.7882x; 1.2659x over previous
//
#include <hip/hip_runtime.h>
#include <hip/hip_bf16.h>
#include <cstdint>

#define HDIM 128

typedef __bf16 bf16x8 __attribute__((ext_vector_type(8)));
typedef unsigned short usx8 __attribute__((ext_vector_type(8)));
typedef float fx4 __attribute__((ext_vector_type(4)));

__device__ __forceinline__ float bf2f(unsigned short u) {
    unsigned int x = ((unsigned int)u) << 16;
    return __uint_as_float(x);
}
__device__ __forceinline__ unsigned short f2bf(float f) {
    unsigned int x = __float_as_uint(f);
    x += 0x7fffu + ((x >> 16) & 1u);
    return (unsigned short)(x >> 16);
}

// ---------------- init + dtype detection ----------------
// flags[0]=1 if float tensors are bf16 (else fp32); flags[1]=1 if ints are int64
__global__ void init_all(const unsigned int* __restrict__ xw,
                         const unsigned int* __restrict__ eiw, int* __restrict__ flags,
                         int* __restrict__ cnti, float* __restrict__ gsumAll, int n) {
    int i = blockIdx.x * blockDim.x + threadIdx.x;
    if (i < n) cnti[i] = 0;
    if (i < 768) gsumAll[i] = 0.f;
    if (blockIdx.x == 0 && threadIdx.x == 0) {
        int sane = 0;
        for (int k = 0; k < 64; k++) {
            unsigned int w = xw[k];
            unsigned short ss[2] = {(unsigned short)(w & 0xffffu), (unsigned short)(w >> 16)};
            for (int q = 0; q < 2; q++) {
                int e = (ss[q] >> 7) & 0xFF;
                if ((ss[q] & 0x7fffu) == 0 || (e >= 100 && e <= 140)) sane++;
            }
        }
        flags[0] = (sane >= 110) ? 1 : 0;
        int zeros = 0;
        for (int k = 1; k < 64; k += 2)
            if (eiw[k] == 0) zeros++;
        flags[1] = (zeros >= 24) ? 1 : 0;
    }
}

struct ParamTab {
    const void* p[18];
    int n[18];
    int off[18];
};
__global__ void convert_params(ParamTab t, unsigned short* __restrict__ dst,
                               const int* __restrict__ flags) {
    int b = blockIdx.x;
    const void* src = t.p[b];
    int n = t.n[b];
    unsigned short* o = dst + t.off[b];
    if (flags[0]) {
        const unsigned short* s = (const unsigned short*)src;
        for (int i = threadIdx.x; i < n; i += blockDim.x) o[i] = s[i];
    } else {
        const float* s = (const float*)src;
        for (int i = threadIdx.x; i < n; i += blockDim.x) o[i] = f2bf(s[i]);
    }
}

// ---------------- degree count + per-edge rank ----------------
__global__ void acc_deg(const void* __restrict__ ei, int* __restrict__ cnti,
                        int* __restrict__ rank, const int* __restrict__ flags, int e) {
    int i = blockIdx.x * blockDim.x + threadIdx.x;
    if (i >= e) return;
    int d = flags[1] ? (int)((const long long*)ei)[e + i] : ((const int*)ei)[e + i];
    rank[i] = atomicAdd(&cnti[d], 1);
}

// ---------------- scan over cnti (+ dis computation fused into scan1) ----------------
__global__ void scan1(const int* __restrict__ cnt, int* __restrict__ part,
                      float* __restrict__ dis, int n) {
    __shared__ int ls[256];
    int b = blockIdx.x, t = threadIdx.x;
    int base = b * 1024;
    int s = 0;
    for (int j = t; j < 1024; j += 256) {
        int i = base + j;
        if (i < n) {
            int c = cnt[i];
            s += c;
            dis[i] = rsqrtf((float)(c + 1));
        }
    }
    ls[t] = s;
    __syncthreads();
    for (int o = 128; o > 0; o >>= 1) {
        if (t < o) ls[t] += ls[t + o];
        __syncthreads();
    }
    if (t == 0) part[b] = ls[0];
}
__global__ void scan2(int* part, int nb) {
    __shared__ int ls[128];
    int t = threadIdx.x;
    int orig = (t < nb) ? part[t] : 0;
    ls[t] = orig;
    __syncthreads();
    for (int o = 1; o < 128; o <<= 1) {
        int v = (t >= o) ? ls[t - o] : 0;
        __syncthreads();
        ls[t] += v;
        __syncthreads();
    }
    if (t < nb) part[t] = ls[t] - orig;  // exclusive
}
__global__ void scan3(const int* __restrict__ cnt, const int* __restrict__ part,
                      int* __restrict__ off, int n) {
    __shared__ int ls[256];
    __shared__ int excl[256];
    int b = blockIdx.x, t = threadIdx.x;
    int i0 = b * 1024 + t * 4;
    int c0 = (i0 + 0 < n) ? cnt[i0 + 0] : 0;
    int c1 = (i0 + 1 < n) ? cnt[i0 + 1] : 0;
    int c2 = (i0 + 2 < n) ? cnt[i0 + 2] : 0;
    int c3 = (i0 + 3 < n) ? cnt[i0 + 3] : 0;
    ls[t] = c0 + c1 + c2 + c3;
    __syncthreads();
    if (t == 0) {
        int acc = 0;
        for (int j = 0; j < 256; j++) { excl[j] = acc; acc += ls[j]; }
    }
    __syncthreads();
    int base = part[b] + excl[t];
    if (i0 + 0 < n) { off[i0 + 0] = base; base += c0; }
    if (i0 + 1 < n) { off[i0 + 1] = base; base += c1; }
    if (i0 + 2 < n) { off[i0 + 2] = base; base += c2; }
    if (i0 + 3 < n) { off[i0 + 3] = base; }
}

// ---------------- CSR fill: no atomics, single 4B scatter ----------------
__global__ void fill_csr(const void* __restrict__ ei, const int* __restrict__ rank,
                         const int* __restrict__ offs, int* __restrict__ csrc,
                         const int* __restrict__ flags, int e) {
    int i = blockIdx.x * blockDim.x + threadIdx.x;
    if (i >= e) return;
    int s, d;
    if (flags[1]) {
        s = (int)((const long long*)ei)[i];
        d = (int)((const long long*)ei)[e + i];
    } else {
        s = ((const int*)ei)[i];
        d = ((const int*)ei)[e + i];
    }
    csrc[offs[d] + rank[i]] = s;
}

// ---------------- graph boundaries via binary search (batch is sorted) ----------------
__global__ void gbounds(const void* __restrict__ batch, const int* __restrict__ flags,
                        int* __restrict__ goff, int* __restrict__ gcnt, int n, int g) {
    int gi = blockIdx.x * blockDim.x + threadIdx.x;
    if (gi >= g) return;
    bool i64 = flags[1] != 0;
    auto getb = [&](int i) -> int {
        return i64 ? (int)((const long long*)batch)[i] : ((const int*)batch)[i];
    };
    auto lower = [&](int val) -> int {
        int lo = 0, hi = n;
        while (lo < hi) {
            int mid = (lo + hi) >> 1;
            if (getb(mid) < val) lo = mid + 1;
            else hi = mid;
        }
        return lo;
    };
    int lo = lower(gi), hi = lower(gi + 1);
    goff[gi] = lo;
    gcnt[gi] = hi - lo;
}

// ---------------- weight repack to MFMA B-fragment order ----------------
__global__ void repack(const unsigned short* __restrict__ wconv, unsigned short* __restrict__ Wf) {
    int idx = blockIdx.x * blockDim.x + threadIdx.x;
    if (idx >= 3 * 2048) return;
    int layer = idx >> 11;
    int rem = idx & 2047;
    int kt = rem >> 9;
    int nt = (rem >> 6) & 7;
    int lane = rem & 63;
    const unsigned short* W = wconv + layer * HDIM * HDIM;
    int row = lane & 15, quad = lane >> 4;
    unsigned short* o = Wf + ((size_t)layer * 2048 + (size_t)((kt * 8 + nt) * 64 + lane)) * 8;
#pragma unroll
    for (int j = 0; j < 8; j++) {
        int k = kt * 32 + quad * 8 + j;
        o[j] = W[k * HDIM + nt * 16 + row];
    }
}

// ---------------- GEMM: C[m,:] = dis[m] * (pre(A)[m,:] @ W), bf16 MFMA ----------------
// l0mode: input is raw x (bf16 or fp32 per flags); else input bf16 + fused BN+ReLU
__global__ __launch_bounds__(256) void mm_mfma(const void* __restrict__ A,
                                               const unsigned short* __restrict__ Wf,
                                               unsigned short* __restrict__ C, int M,
                                               const float* __restrict__ sc,
                                               const float* __restrict__ sh,
                                               const float* __restrict__ dis,
                                               const int* __restrict__ flags, int l0mode) {
    int gid = blockIdx.x * blockDim.x + threadIdx.x;
    int wave = gid >> 6;
    int lane = threadIdx.x & 63;
    int m0 = wave * 16;
    if (m0 >= M) return;
    int row = lane & 15, quad = lane >> 4;
    bool xfp32 = l0mode && !flags[0];
    const unsigned short* arow =
        (const unsigned short*)A + (size_t)(m0 + row) * HDIM + quad * 8;
    const float* arowf = (const float*)A + (size_t)(m0 + row) * HDIM + quad * 8;
    fx4 acc[8];
#pragma unroll
    for (int t = 0; t < 8; t++) acc[t] = (fx4){0.f, 0.f, 0.f, 0.f};
#pragma unroll
    for (int kt = 0; kt < 4; kt++) {
        bf16x8 a;
        if (xfp32) {
            fx4 f0 = *(const fx4*)(arowf + kt * 32);
            fx4 f1 = *(const fx4*)(arowf + kt * 32 + 4);
            usx8 t;
#pragma unroll
            for (int q = 0; q < 4; q++) t[q] = f2bf(f0[q]);
#pragma unroll
            for (int q = 0; q < 4; q++) t[4 + q] = f2bf(f1[q]);
            a = __builtin_bit_cast(bf16x8, t);
        } else {
            usx8 raw = *(const usx8*)(arow + kt * 32);
            if (!l0mode) {
                int col = kt * 32 + quad * 8;
                fx4 s0 = *(const fx4*)(sc + col);
                fx4 s1 = *(const fx4*)(sc + col + 4);
                fx4 h0 = *(const fx4*)(sh + col);
                fx4 h1 = *(const fx4*)(sh + col + 4);
                usx8 t;
#pragma unroll
                for (int q = 0; q < 4; q++)
                    t[q] = f2bf(fmaxf(s0[q] * bf2f(raw[q]) + h0[q], 0.f));
#pragma unroll
                for (int q = 0; q < 4; q++)
                    t[4 + q] = f2bf(fmaxf(s1[q] * bf2f(raw[4 + q]) + h1[q], 0.f));
                a = __builtin_bit_cast(bf16x8, t);
            } else {
                a = __builtin_bit_cast(bf16x8, raw);
            }
        }
        const unsigned short* wf = Wf + ((size_t)(kt * 8) * 64 + lane) * 8;
#pragma unroll
        for (int nt = 0; nt < 8; nt++) {
            bf16x8 b = __builtin_bit_cast(bf16x8, *(const usx8*)(wf + (size_t)nt * 64 * 8));
            acc[nt] = __builtin_amdgcn_mfma_f32_16x16x32_bf16(a, b, acc[nt], 0, 0, 0);
        }
    }
    float dsc[4];
#pragma unroll
    for (int r = 0; r < 4; r++) dsc[r] = dis[m0 + quad * 4 + r];
#pragma unroll
    for (int nt = 0; nt < 8; nt++) {
        int col = nt * 16 + row;
#pragma unroll
        for (int r = 0; r < 4; r++) {
            int m = m0 + quad * 4 + r;
            C[(size_t)m * HDIM + col] = f2bf(acc[nt][r] * dsc[r]);
        }
    }
}

// ---------------- aggregation: out[i] = bias + dis[i]*(h'[i] + sum h'[nbr]) ----------------
__global__ __launch_bounds__(256) void aggregate(const unsigned short* __restrict__ hw,
                                                 const float* __restrict__ dis,
                                                 const int* __restrict__ offs,
                                                 const int* __restrict__ cnt,
                                                 const int* __restrict__ csrc,
                                                 const unsigned short* __restrict__ bias,
                                                 unsigned short* __restrict__ agg, int n) {
    int wv = (blockIdx.x * blockDim.x + threadIdx.x) >> 6;
    int lane = threadIdx.x & 63;
    int grp = lane >> 4, sub = lane & 15;
    int node = wv * 4 + grp;
    if (node >= n) return;
    int colb = sub * 8;
    usx8 sv = *(const usx8*)(hw + (size_t)node * HDIM + colb);
    float a[8];
#pragma unroll
    for (int q = 0; q < 8; q++) a[q] = bf2f(sv[q]);
    int o = offs[node], c = cnt[node];
    int s0 = 0, s1 = 0;
    if (c > 0) s0 = csrc[o];
    if (c > 1) s1 = csrc[o + 1];
    for (int j = 0; j < c; j++) {
        usx8 v = *(const usx8*)(hw + (size_t)s0 * HDIM + colb);
        int s2 = 0;
        if (j + 2 < c) s2 = csrc[o + j + 2];
#pragma unroll
        for (int q = 0; q < 8; q++) a[q] += bf2f(v[q]);
        s0 = s1;
        s1 = s2;
    }
    float di = dis[node];
    usx8 bv = *(const usx8*)(bias + colb);
    usx8 ov;
#pragma unroll
    for (int q = 0; q < 8; q++) ov[q] = f2bf(bf2f(bv[q]) + di * a[q]);
    *(usx8*)(agg + (size_t)node * HDIM + colb) = ov;
}

// ---------------- BN stats / finalize ----------------
__global__ void col_stats(const unsigned short* __restrict__ agg, float* __restrict__ gsum,
                          float* __restrict__ gsq, int n) {
    int t = threadIdx.x;
    int c = t & 127, p = t >> 7;
    float s = 0.f, s2 = 0.f;
    int stride = gridDim.x * 2;
    for (int r = blockIdx.x * 2 + p; r < n; r += stride) {
        float v = bf2f(agg[(size_t)r * HDIM + c]);
        s += v;
        s2 += v * v;
    }
    __shared__ float ls[256], ls2[256];
    ls[t] = s;
    ls2[t] = s2;
    __syncthreads();
    if (t < 128) {
        atomicAdd(&gsum[t], ls[t] + ls[t + 128]);
        atomicAdd(&gsq[t], ls2[t] + ls2[t + 128]);
    }
}
__global__ void bn_finalize(const float* __restrict__ gsum, const float* __restrict__ gsq,
                            const unsigned short* __restrict__ g,
                            const unsigned short* __restrict__ be,
                            float* __restrict__ sc, float* __restrict__ sh, float invn) {
    int c = threadIdx.x;
    if (c < 128) {
        float m = gsum[c] * invn;
        float v = gsq[c] * invn - m * m;
        float s = bf2f(g[c]) * rsqrtf(v + 1e-5f);
        sc[c] = s;
        sh[c] = bf2f(be[c]) - m * s;
    }
}

// ---------------- pooling (fused BN3+ReLU) + head ----------------
__global__ void pool(const unsigned short* __restrict__ hin, const int* __restrict__ goff,
                     const int* __restrict__ gcnt, const float* __restrict__ sc,
                     const float* __restrict__ sh, float* __restrict__ pooled) {
    int g = blockIdx.x, t = threadIdx.x;
    int c = t & 127, p = t >> 7;
    float scale = sc[c], shift = sh[c];
    int s = goff[g], cn = gcnt[g];
    float acc = 0.f;
    for (int r = s + p; r < s + cn; r += 2)
        acc += fmaxf(scale * bf2f(hin[(size_t)r * HDIM + c]) + shift, 0.f);
    __shared__ float ls[256];
    ls[t] = acc;
    __syncthreads();
    if (t < 128) pooled[(size_t)g * HDIM + t] = (ls[t] + ls[t + 128]) / fmaxf((float)cn, 1.f);
}
__global__ void pooled_bn(const float* __restrict__ pooled, const unsigned short* __restrict__ g,
                          const unsigned short* __restrict__ be, float* __restrict__ psc,
                          float* __restrict__ psh, int G_) {
    int t = threadIdx.x;
    int c = t & 127, p = t >> 7;
    float s = 0.f, s2 = 0.f;
    for (int r = p; r < G_; r += 4) {
        float v = pooled[(size_t)r * HDIM + c];
        s += v;
        s2 += v * v;
    }
    __shared__ float ls[512], ls2[512];
    ls[t] = s;
    ls2[t] = s2;
    __syncthreads();
    if (t < 128) {
        float S = ls[t] + ls[t + 128] + ls[t + 256] + ls[t + 384];
        float S2 = ls2[t] + ls2[t + 128] + ls2[t + 256] + ls2[t + 384];
        float m = S / (float)G_;
        float v = S2 / (float)G_ - m * m;
        float sc = bf2f(g[t]) * rsqrtf(v + 1e-5f);
        psc[t] = sc;
        psh[t] = bf2f(be[t]) - m * sc;
    }
}
__global__ void mlp1(const float* __restrict__ pooled, const float* __restrict__ psc,
                     const float* __restrict__ psh, const unsigned short* __restrict__ lw1,
                     const unsigned short* __restrict__ lb1, float* __restrict__ z1) {
    int r = blockIdx.x, t = threadIdx.x;
    __shared__ float row[128];
    row[t] = psc[t] * pooled[(size_t)r * HDIM + t] + psh[t];
    __syncthreads();
    float acc = bf2f(lb1[t]);
    for (int k = 0; k < 128; k++) acc += row[k] * bf2f(lw1[k * HDIM + t]);
    z1[(size_t)r * HDIM + t] = fmaxf(acc, 0.f);
}
__global__ void mlp2(const float* __restrict__ z1, const unsigned short* __restrict__ lw2,
                     const unsigned short* __restrict__ lb2, void* __restrict__ out,
                     const int* __restrict__ flags) {
    int r = blockIdx.x, t = threadIdx.x;
    __shared__ float row[128];
    __shared__ float z2[10];
    __shared__ float lse;
    row[t] = z1[(size_t)r * HDIM + t];
    __syncthreads();
    if (t < 10) {
        float a = bf2f(lb2[t]);
        for (int k = 0; k < 128; k++) a += row[k] * bf2f(lw2[k * 10 + t]);
        z2[t] = a;
    }
    __syncthreads();
    if (t == 0) {
        float m = z2[0];
        for (int j = 1; j < 10; j++) m = fmaxf(m, z2[j]);
        float s = 0.f;
        for (int j = 0; j < 10; j++) s += expf(z2[j] - m);
        lse = m + logf(s);
    }
    __syncthreads();
    if (t < 10) {
        float v = z2[t] - lse;
        if (flags[0]) ((unsigned short*)out)[r * 10 + t] = f2bf(v);
        else ((float*)out)[r * 10 + t] = v;
    }
}

extern "C" void kernel_launch(void* const* d_in, const int* in_sizes, int n_in,
                              void* d_out, int out_size, void* d_ws, size_t ws_size,
                              hipStream_t stream) {
    const void* x = d_in[0];
    const void* ei = d_in[1];
    const void* batch = d_in[2];

    int N_ = in_sizes[2];
    int E_ = in_sizes[1] / 2;
    int G_ = out_size / 10;

    char* ws = (char*)d_ws;
    auto alloc = [&](size_t bytes) -> char* {
        char* p = ws;
        ws += (bytes + 255) & ~(size_t)255;
        return p;
    };
    int* flags = (int*)alloc(256);
    float* dis = (float*)alloc((size_t)N_ * 4);
    int* cnti = (int*)alloc((size_t)N_ * 4);
    int* offs = (int*)alloc((size_t)N_ * 4);
    int* part = (int*)alloc(4096);
    int* rank = (int*)alloc((size_t)E_ * 4);
    int* csrc = (int*)alloc((size_t)E_ * 4);
    unsigned short* hw = (unsigned short*)alloc((size_t)N_ * HDIM * 2);
    unsigned short* aggbuf = (unsigned short*)alloc((size_t)N_ * HDIM * 2);
    unsigned short* wconv = (unsigned short*)alloc(70000 * 2);
    unsigned short* wfrag = (unsigned short*)alloc(3 * HDIM * HDIM * 2);
    float* gsumAll = (float*)alloc(768 * 4);
    float* bsc = (float*)alloc(128 * 4);
    float* bsh = (float*)alloc(128 * 4);
    int* gcnt = (int*)alloc((size_t)G_ * 4);
    int* goff = (int*)alloc((size_t)G_ * 4);
    float* pooled = (float*)alloc((size_t)G_ * HDIM * 4);
    float* psc = (float*)alloc(128 * 4);
    float* psh = (float*)alloc(128 * 4);
    float* z1 = (float*)alloc((size_t)G_ * HDIM * 4);

    // wconv layout (element offsets)
    const int oW = 0;
    const int oB = 49152;
    const int oLB1 = oB + 1408;
    const int oLW1 = oLB1 + 128;
    const int oLW2 = oLW1 + 16384;
    const int oLB2 = oLW2 + 1280;

    int nb256 = (N_ + 255) / 256;
    int eb256 = (E_ + 255) / 256;
    int nblk = (N_ + 1023) / 1024;

    init_all<<<nb256, 256, 0, stream>>>((const unsigned int*)x, (const unsigned int*)ei, flags,
                                        cnti, gsumAll, N_);

    ParamTab tab;
    const int srcIdx[18] = {3, 7, 11, 4, 5, 6, 8, 9, 10, 12, 13, 14, 15, 16, 18, 17, 19, 20};
    const int dstOff[18] = {oW, oW + 16384, oW + 32768,
                            oB + 0, oB + 128, oB + 256,
                            oB + 384, oB + 512, oB + 640,
                            oB + 768, oB + 896, oB + 1024,
                            oB + 1152, oB + 1280,
                            oLB1, oLW1, oLW2, oLB2};
    for (int i = 0; i < 18; i++) {
        tab.p[i] = d_in[srcIdx[i]];
        tab.n[i] = in_sizes[srcIdx[i]];
        tab.off[i] = dstOff[i];
    }
    convert_params<<<18, 256, 0, stream>>>(tab, wconv, flags);

    acc_deg<<<eb256, 256, 0, stream>>>(ei, cnti, rank, flags, E_);
    scan1<<<nblk, 256, 0, stream>>>(cnti, part, dis, N_);
    scan2<<<1, 128, 0, stream>>>(part, nblk);
    scan3<<<nblk, 256, 0, stream>>>(cnti, part, offs, N_);
    fill_csr<<<eb256, 256, 0, stream>>>(ei, rank, offs, csrc, flags, E_);

    gbounds<<<(G_ + 255) / 256, 256, 0, stream>>>(batch, flags, goff, gcnt, N_, G_);

    repack<<<(3 * 2048 + 255) / 256, 256, 0, stream>>>(wconv, wfrag);

    int mm_blocks = (((N_ + 15) / 16) * 64 + 255) / 256;
    int agg_blocks = (N_ + 15) / 16;  // 4 nodes/wave, 4 waves/block
    float invn = 1.f / (float)N_;

    for (int l = 0; l < 3; l++) {
        const void* A = (l == 0) ? x : (const void*)aggbuf;
        mm_mfma<<<mm_blocks, 256, 0, stream>>>(A, wfrag + (size_t)l * HDIM * HDIM, hw, N_,
                                               bsc, bsh, dis, flags, (l == 0) ? 1 : 0);
        aggregate<<<agg_blocks, 256, 0, stream>>>(hw, dis, offs, cnti, csrc,
                                                  wconv + oB + l * 384, aggbuf, N_);
        float* gsum = gsumAll + l * 256;
        col_stats<<<512, 256, 0, stream>>>(aggbuf, gsum, gsum + 128, N_);
        bn_finalize<<<1, 128, 0, stream>>>(gsum, gsum + 128, wconv + oB + l * 384 + 128,
                                           wconv + oB + l * 384 + 256, bsc, bsh, invn);
    }

    pool<<<G_, 256, 0, stream>>>(aggbuf, goff, gcnt, bsc, bsh, pooled);
    pooled_bn<<<1, 512, 0, stream>>>(pooled, wconv + oB + 1152, wconv + oB + 1280, psc, psh, G_);
    mlp1<<<G_, 128, 0, stream>>>(pooled, psc, psh, wconv + oLW1, wconv + oLB1, z1);
    mlp2<<<G_, 128, 0, stream>>>(z1, wconv + oLW2, wconv + oLB2, d_out, flags);
}

// Round 5
// 659.671 us; speedup vs baseline: 1.9061x; 1.0659x over previous
//
#include <hip/hip_runtime.h>
#include <hip/hip_bf16.h>
#include <cstdint>

#define HDIM 128

typedef __bf16 bf16x8 __attribute__((ext_vector_type(8)));
typedef unsigned short usx8 __attribute__((ext_vector_type(8)));
typedef float fx4 __attribute__((ext_vector_type(4)));

__device__ __forceinline__ float bf2f(unsigned short u) {
    unsigned int x = ((unsigned int)u) << 16;
    return __uint_as_float(x);
}
__device__ __forceinline__ unsigned short f2bf(float f) {
    unsigned int x = __float_as_uint(f);
    x += 0x7fffu + ((x >> 16) & 1u);
    return (unsigned short)(x >> 16);
}

// ---------------- init + dtype detection ----------------
// flags[0]=1 if float tensors are bf16 (else fp32); flags[1]=1 if ints are int64
__global__ void init_all(const unsigned int* __restrict__ xw,
                         const unsigned int* __restrict__ eiw, int* __restrict__ flags,
                         float* __restrict__ gsumAll) {
    int i = blockIdx.x * blockDim.x + threadIdx.x;
    if (i < 768) gsumAll[i] = 0.f;
    if (i == 0) {
        int sane = 0;
        for (int k = 0; k < 64; k++) {
            unsigned int w = xw[k];
            unsigned short ss[2] = {(unsigned short)(w & 0xffffu), (unsigned short)(w >> 16)};
            for (int q = 0; q < 2; q++) {
                int e = (ss[q] >> 7) & 0xFF;
                if ((ss[q] & 0x7fffu) == 0 || (e >= 100 && e <= 140)) sane++;
            }
        }
        flags[0] = (sane >= 110) ? 1 : 0;
        int zeros = 0;
        for (int k = 1; k < 64; k += 2)
            if (eiw[k] == 0) zeros++;
        flags[1] = (zeros >= 24) ? 1 : 0;
    }
}

struct ParamTab {
    const void* p[18];
    int n[18];
    int off[18];
};
__global__ void convert_params(ParamTab t, unsigned short* __restrict__ dst,
                               const int* __restrict__ flags) {
    int b = blockIdx.x;
    const void* src = t.p[b];
    int n = t.n[b];
    unsigned short* o = dst + t.off[b];
    if (flags[0]) {
        const unsigned short* s = (const unsigned short*)src;
        for (int i = threadIdx.x; i < n; i += blockDim.x) o[i] = s[i];
    } else {
        const float* s = (const float*)src;
        for (int i = threadIdx.x; i < n; i += blockDim.x) o[i] = f2bf(s[i]);
    }
}

// ================= CSR build: 2-pass bucket sort, zero global atomics =================
// bucket = dst >> 9 (512 nodes/bucket). Tile = 2048 edges.
// Ct[bucket*ntiles + tile] = count; after scan, exclusive global offset.

__global__ void p1_hist(const void* __restrict__ ei, const int* __restrict__ flags,
                        int* __restrict__ Ct, int E, int NB, int ntiles) {
    __shared__ int h[1024];
    int tile = blockIdx.x, t = threadIdx.x;
    for (int i = t; i < NB; i += 256) h[i] = 0;
    __syncthreads();
    int base = tile * 2048;
    bool i64 = flags[1] != 0;
    for (int i = t; i < 2048; i += 256) {
        int idx = base + i;
        if (idx < E) {
            int d = i64 ? (int)((const long long*)ei)[E + idx] : ((const int*)ei)[E + idx];
            atomicAdd(&h[d >> 9], 1);
        }
    }
    __syncthreads();
    for (int b = t; b < NB; b += 256) Ct[b * ntiles + tile] = h[b];
}

__global__ void scanA(const int* __restrict__ d, int* __restrict__ part, int L) {
    __shared__ int ls[256];
    int b = blockIdx.x, t = threadIdx.x;
    int base = b * 2048;
    int s = 0;
    for (int j = t; j < 2048; j += 256) {
        int i = base + j;
        if (i < L) s += d[i];
    }
    ls[t] = s;
    __syncthreads();
    for (int o = 128; o > 0; o >>= 1) {
        if (t < o) ls[t] += ls[t + o];
        __syncthreads();
    }
    if (t == 0) part[b] = ls[0];
}
__global__ void scan2(int* part, int nb) {
    __shared__ int ls[128];
    int t = threadIdx.x;
    int orig = (t < nb) ? part[t] : 0;
    ls[t] = orig;
    __syncthreads();
    for (int o = 1; o < 128; o <<= 1) {
        int v = (t >= o) ? ls[t - o] : 0;
        __syncthreads();
        ls[t] += v;
        __syncthreads();
    }
    if (t < nb) part[t] = ls[t] - orig;  // exclusive
}
__global__ void scanC(int* __restrict__ d, const int* __restrict__ part, int L) {
    __shared__ int ls[256];
    __shared__ int excl[256];
    int b = blockIdx.x, t = threadIdx.x;
    int i0 = b * 2048 + t * 8;
    int v[8];
    int s = 0;
#pragma unroll
    for (int q = 0; q < 8; q++) {
        v[q] = (i0 + q < L) ? d[i0 + q] : 0;
        s += v[q];
    }
    ls[t] = s;
    __syncthreads();
    if (t == 0) {
        int a = 0;
        for (int j = 0; j < 256; j++) { excl[j] = a; a += ls[j]; }
    }
    __syncthreads();
    int base = part[b] + excl[t];
#pragma unroll
    for (int q = 0; q < 8; q++) {
        if (i0 + q < L) d[i0 + q] = base;
        base += v[q];
    }
}

__global__ void p1_scatter(const void* __restrict__ ei, const int* __restrict__ flags,
                           const int* __restrict__ Ct, unsigned long long* __restrict__ pairs,
                           int E, int NB, int ntiles) {
    __shared__ int cur[1024];
    int tile = blockIdx.x, t = threadIdx.x;
    for (int i = t; i < NB; i += 256) cur[i] = Ct[i * ntiles + tile];
    __syncthreads();
    int base = tile * 2048;
    bool i64 = flags[1] != 0;
    for (int i = t; i < 2048; i += 256) {
        int idx = base + i;
        if (idx < E) {
            int s, d;
            if (i64) {
                s = (int)((const long long*)ei)[idx];
                d = (int)((const long long*)ei)[E + idx];
            } else {
                s = ((const int*)ei)[idx];
                d = ((const int*)ei)[E + idx];
            }
            int pos = atomicAdd(&cur[d >> 9], 1);
            pairs[pos] = ((unsigned long long)(unsigned)d << 32) | (unsigned)s;
        }
    }
}

// one block per bucket: per-node grouping + offs/cnt/dis
__global__ void p2_build(const unsigned long long* __restrict__ pairs,
                         const int* __restrict__ Ct, int* __restrict__ csrc,
                         int* __restrict__ offs, int* __restrict__ cnt,
                         float* __restrict__ dis, int E, int N, int NB, int ntiles) {
    __shared__ int hist[512];
    __shared__ int start[512];
    __shared__ int cur[512];
    int b = blockIdx.x, t = threadIdx.x;
    int node0 = b * 512;
    for (int i = t; i < 512; i += 256) hist[i] = 0;
    __syncthreads();
    int lo = Ct[b * ntiles];
    int hi = (b + 1 < NB) ? Ct[(b + 1) * ntiles] : E;
    for (int i = lo + t; i < hi; i += 256) {
        int d = (int)(pairs[i] >> 32);
        atomicAdd(&hist[d - node0], 1);
    }
    __syncthreads();
    if (t == 0) {
        int a = 0;
        for (int j = 0; j < 512; j++) { start[j] = a; a += hist[j]; }
    }
    __syncthreads();
    for (int i = t; i < 512; i += 256) {
        cur[i] = 0;
        int node = node0 + i;
        if (node < N) {
            offs[node] = lo + start[i];
            cnt[node] = hist[i];
            dis[node] = rsqrtf((float)(hist[i] + 1));
        }
    }
    __syncthreads();
    for (int i = lo + t; i < hi; i += 256) {
        unsigned long long p = pairs[i];
        int l = (int)(p >> 32) - node0;
        int pos = lo + start[l] + atomicAdd(&cur[l], 1);
        csrc[pos] = (int)(p & 0xffffffffu);
    }
}

// ---------------- graph boundaries via binary search (batch is sorted) ----------------
__global__ void gbounds(const void* __restrict__ batch, const int* __restrict__ flags,
                        int* __restrict__ goff, int* __restrict__ gcnt, int n, int g) {
    int gi = blockIdx.x * blockDim.x + threadIdx.x;
    if (gi >= g) return;
    bool i64 = flags[1] != 0;
    auto getb = [&](int i) -> int {
        return i64 ? (int)((const long long*)batch)[i] : ((const int*)batch)[i];
    };
    auto lower = [&](int val) -> int {
        int lo = 0, hi = n;
        while (lo < hi) {
            int mid = (lo + hi) >> 1;
            if (getb(mid) < val) lo = mid + 1;
            else hi = mid;
        }
        return lo;
    };
    int lo = lower(gi), hi = lower(gi + 1);
    goff[gi] = lo;
    gcnt[gi] = hi - lo;
}

// ---------------- weight repack to MFMA B-fragment order ----------------
__global__ void repack(const unsigned short* __restrict__ wconv, unsigned short* __restrict__ Wf) {
    int idx = blockIdx.x * blockDim.x + threadIdx.x;
    if (idx >= 3 * 2048) return;
    int layer = idx >> 11;
    int rem = idx & 2047;
    int kt = rem >> 9;
    int nt = (rem >> 6) & 7;
    int lane = rem & 63;
    const unsigned short* W = wconv + layer * HDIM * HDIM;
    int row = lane & 15, quad = lane >> 4;
    unsigned short* o = Wf + ((size_t)layer * 2048 + (size_t)((kt * 8 + nt) * 64 + lane)) * 8;
#pragma unroll
    for (int j = 0; j < 8; j++) {
        int k = kt * 32 + quad * 8 + j;
        o[j] = W[k * HDIM + nt * 16 + row];
    }
}

// ---------------- GEMM: C[m,:] = dis[m] * (pre(A)[m,:] @ W), bf16 MFMA ----------------
__global__ __launch_bounds__(256) void mm_mfma(const void* __restrict__ A,
                                               const unsigned short* __restrict__ Wf,
                                               unsigned short* __restrict__ C, int M,
                                               const float* __restrict__ sc,
                                               const float* __restrict__ sh,
                                               const float* __restrict__ dis,
                                               const int* __restrict__ flags, int l0mode) {
    int gid = blockIdx.x * blockDim.x + threadIdx.x;
    int wave = gid >> 6;
    int lane = threadIdx.x & 63;
    int m0 = wave * 16;
    if (m0 >= M) return;
    int row = lane & 15, quad = lane >> 4;
    bool xfp32 = l0mode && !flags[0];
    const unsigned short* arow =
        (const unsigned short*)A + (size_t)(m0 + row) * HDIM + quad * 8;
    const float* arowf = (const float*)A + (size_t)(m0 + row) * HDIM + quad * 8;
    fx4 acc[8];
#pragma unroll
    for (int t = 0; t < 8; t++) acc[t] = (fx4){0.f, 0.f, 0.f, 0.f};
#pragma unroll
    for (int kt = 0; kt < 4; kt++) {
        bf16x8 a;
        if (xfp32) {
            fx4 f0 = *(const fx4*)(arowf + kt * 32);
            fx4 f1 = *(const fx4*)(arowf + kt * 32 + 4);
            usx8 t;
#pragma unroll
            for (int q = 0; q < 4; q++) t[q] = f2bf(f0[q]);
#pragma unroll
            for (int q = 0; q < 4; q++) t[4 + q] = f2bf(f1[q]);
            a = __builtin_bit_cast(bf16x8, t);
        } else {
            usx8 raw = *(const usx8*)(arow + kt * 32);
            if (!l0mode) {
                int col = kt * 32 + quad * 8;
                fx4 s0 = *(const fx4*)(sc + col);
                fx4 s1 = *(const fx4*)(sc + col + 4);
                fx4 h0 = *(const fx4*)(sh + col);
                fx4 h1 = *(const fx4*)(sh + col + 4);
                usx8 t;
#pragma unroll
                for (int q = 0; q < 4; q++)
                    t[q] = f2bf(fmaxf(s0[q] * bf2f(raw[q]) + h0[q], 0.f));
#pragma unroll
                for (int q = 0; q < 4; q++)
                    t[4 + q] = f2bf(fmaxf(s1[q] * bf2f(raw[4 + q]) + h1[q], 0.f));
                a = __builtin_bit_cast(bf16x8, t);
            } else {
                a = __builtin_bit_cast(bf16x8, raw);
            }
        }
        const unsigned short* wf = Wf + ((size_t)(kt * 8) * 64 + lane) * 8;
#pragma unroll
        for (int nt = 0; nt < 8; nt++) {
            bf16x8 b = __builtin_bit_cast(bf16x8, *(const usx8*)(wf + (size_t)nt * 64 * 8));
            acc[nt] = __builtin_amdgcn_mfma_f32_16x16x32_bf16(a, b, acc[nt], 0, 0, 0);
        }
    }
    float dsc[4];
#pragma unroll
    for (int r = 0; r < 4; r++) dsc[r] = dis[m0 + quad * 4 + r];
#pragma unroll
    for (int nt = 0; nt < 8; nt++) {
        int col = nt * 16 + row;
#pragma unroll
        for (int r = 0; r < 4; r++) {
            int m = m0 + quad * 4 + r;
            C[(size_t)m * HDIM + col] = f2bf(acc[nt][r] * dsc[r]);
        }
    }
}

// ---------------- aggregation: out[i] = bias + dis[i]*(h'[i] + sum h'[nbr]) ----------------
__global__ __launch_bounds__(256) void aggregate(const unsigned short* __restrict__ hw,
                                                 const float* __restrict__ dis,
                                                 const int* __restrict__ offs,
                                                 const int* __restrict__ cnt,
                                                 const int* __restrict__ csrc,
                                                 const unsigned short* __restrict__ bias,
                                                 unsigned short* __restrict__ agg, int n) {
    int wv = (blockIdx.x * blockDim.x + threadIdx.x) >> 6;
    int lane = threadIdx.x & 63;
    int grp = lane >> 4, sub = lane & 15;
    int node = wv * 4 + grp;
    if (node >= n) return;
    int colb = sub * 8;
    usx8 sv = *(const usx8*)(hw + (size_t)node * HDIM + colb);
    float a[8];
#pragma unroll
    for (int q = 0; q < 8; q++) a[q] = bf2f(sv[q]);
    int o = offs[node], c = cnt[node];
    int s0 = 0, s1 = 0;
    if (c > 0) s0 = csrc[o];
    if (c > 1) s1 = csrc[o + 1];
    for (int j = 0; j < c; j++) {
        usx8 v = *(const usx8*)(hw + (size_t)s0 * HDIM + colb);
        int s2 = 0;
        if (j + 2 < c) s2 = csrc[o + j + 2];
#pragma unroll
        for (int q = 0; q < 8; q++) a[q] += bf2f(v[q]);
        s0 = s1;
        s1 = s2;
    }
    float di = dis[node];
    usx8 bv = *(const usx8*)(bias + colb);
    usx8 ov;
#pragma unroll
    for (int q = 0; q < 8; q++) ov[q] = f2bf(bf2f(bv[q]) + di * a[q]);
    *(usx8*)(agg + (size_t)node * HDIM + colb) = ov;
}

// ---------------- BN stats / finalize ----------------
__global__ void col_stats(const unsigned short* __restrict__ agg, float* __restrict__ gsum,
                          float* __restrict__ gsq, int n) {
    int t = threadIdx.x;
    int c = t & 127, p = t >> 7;
    float s = 0.f, s2 = 0.f;
    int stride = gridDim.x * 2;
    for (int r = blockIdx.x * 2 + p; r < n; r += stride) {
        float v = bf2f(agg[(size_t)r * HDIM + c]);
        s += v;
        s2 += v * v;
    }
    __shared__ float ls[256], ls2[256];
    ls[t] = s;
    ls2[t] = s2;
    __syncthreads();
    if (t < 128) {
        atomicAdd(&gsum[t], ls[t] + ls[t + 128]);
        atomicAdd(&gsq[t], ls2[t] + ls2[t + 128]);
    }
}
__global__ void bn_finalize(const float* __restrict__ gsum, const float* __restrict__ gsq,
                            const unsigned short* __restrict__ g,
                            const unsigned short* __restrict__ be,
                            float* __restrict__ sc, float* __restrict__ sh, float invn) {
    int c = threadIdx.x;
    if (c < 128) {
        float m = gsum[c] * invn;
        float v = gsq[c] * invn - m * m;
        float s = bf2f(g[c]) * rsqrtf(v + 1e-5f);
        sc[c] = s;
        sh[c] = bf2f(be[c]) - m * s;
    }
}

// ---------------- pooling (fused BN3+ReLU) + head ----------------
__global__ void pool(const unsigned short* __restrict__ hin, const int* __restrict__ goff,
                     const int* __restrict__ gcnt, const float* __restrict__ sc,
                     const float* __restrict__ sh, float* __restrict__ pooled) {
    int g = blockIdx.x, t = threadIdx.x;
    int c = t & 127, p = t >> 7;
    float scale = sc[c], shift = sh[c];
    int s = goff[g], cn = gcnt[g];
    float acc = 0.f;
    for (int r = s + p; r < s + cn; r += 2)
        acc += fmaxf(scale * bf2f(hin[(size_t)r * HDIM + c]) + shift, 0.f);
    __shared__ float ls[256];
    ls[t] = acc;
    __syncthreads();
    if (t < 128) pooled[(size_t)g * HDIM + t] = (ls[t] + ls[t + 128]) / fmaxf((float)cn, 1.f);
}
__global__ void pooled_bn(const float* __restrict__ pooled, const unsigned short* __restrict__ g,
                          const unsigned short* __restrict__ be, float* __restrict__ psc,
                          float* __restrict__ psh, int G_) {
    int t = threadIdx.x;
    int c = t & 127, p = t >> 7;
    float s = 0.f, s2 = 0.f;
    for (int r = p; r < G_; r += 4) {
        float v = pooled[(size_t)r * HDIM + c];
        s += v;
        s2 += v * v;
    }
    __shared__ float ls[512], ls2[512];
    ls[t] = s;
    ls2[t] = s2;
    __syncthreads();
    if (t < 128) {
        float S = ls[t] + ls[t + 128] + ls[t + 256] + ls[t + 384];
        float S2 = ls2[t] + ls2[t + 128] + ls2[t + 256] + ls2[t + 384];
        float m = S / (float)G_;
        float v = S2 / (float)G_ - m * m;
        float sc = bf2f(g[t]) * rsqrtf(v + 1e-5f);
        psc[t] = sc;
        psh[t] = bf2f(be[t]) - m * sc;
    }
}
__global__ void mlp1(const float* __restrict__ pooled, const float* __restrict__ psc,
                     const float* __restrict__ psh, const unsigned short* __restrict__ lw1,
                     const unsigned short* __restrict__ lb1, float* __restrict__ z1) {
    int r = blockIdx.x, t = threadIdx.x;
    __shared__ float row[128];
    row[t] = psc[t] * pooled[(size_t)r * HDIM + t] + psh[t];
    __syncthreads();
    float acc = bf2f(lb1[t]);
    for (int k = 0; k < 128; k++) acc += row[k] * bf2f(lw1[k * HDIM + t]);
    z1[(size_t)r * HDIM + t] = fmaxf(acc, 0.f);
}
__global__ void mlp2(const float* __restrict__ z1, const unsigned short* __restrict__ lw2,
                     const unsigned short* __restrict__ lb2, void* __restrict__ out,
                     const int* __restrict__ flags) {
    int r = blockIdx.x, t = threadIdx.x;
    __shared__ float row[128];
    __shared__ float z2[10];
    __shared__ float lse;
    row[t] = z1[(size_t)r * HDIM + t];
    __syncthreads();
    if (t < 10) {
        float a = bf2f(lb2[t]);
        for (int k = 0; k < 128; k++) a += row[k] * bf2f(lw2[k * 10 + t]);
        z2[t] = a;
    }
    __syncthreads();
    if (t == 0) {
        float m = z2[0];
        for (int j = 1; j < 10; j++) m = fmaxf(m, z2[j]);
        float s = 0.f;
        for (int j = 0; j < 10; j++) s += expf(z2[j] - m);
        lse = m + logf(s);
    }
    __syncthreads();
    if (t < 10) {
        float v = z2[t] - lse;
        if (flags[0]) ((unsigned short*)out)[r * 10 + t] = f2bf(v);
        else ((float*)out)[r * 10 + t] = v;
    }
}

extern "C" void kernel_launch(void* const* d_in, const int* in_sizes, int n_in,
                              void* d_out, int out_size, void* d_ws, size_t ws_size,
                              hipStream_t stream) {
    const void* x = d_in[0];
    const void* ei = d_in[1];
    const void* batch = d_in[2];

    int N_ = in_sizes[2];
    int E_ = in_sizes[1] / 2;
    int G_ = out_size / 10;

    int NB = (N_ + 511) / 512;
    int ntiles = (E_ + 2047) / 2048;
    int L = NB * ntiles;
    int nscan = (L + 2047) / 2048;

    char* ws = (char*)d_ws;
    auto alloc = [&](size_t bytes) -> char* {
        char* p = ws;
        ws += (bytes + 255) & ~(size_t)255;
        return p;
    };
    int* flags = (int*)alloc(256);
    float* dis = (float*)alloc((size_t)N_ * 4);
    int* offs = (int*)alloc((size_t)N_ * 4);
    int* cnt = (int*)alloc((size_t)N_ * 4);
    int* part = (int*)alloc(4096);
    int* Ct = (int*)alloc((size_t)L * 4);
    unsigned long long* pairs = (unsigned long long*)alloc((size_t)E_ * 8);
    int* csrc = (int*)alloc((size_t)E_ * 4);
    unsigned short* hw = (unsigned short*)alloc((size_t)N_ * HDIM * 2);
    unsigned short* aggbuf = (unsigned short*)alloc((size_t)N_ * HDIM * 2);
    unsigned short* wconv = (unsigned short*)alloc(70000 * 2);
    unsigned short* wfrag = (unsigned short*)alloc(3 * HDIM * HDIM * 2);
    float* gsumAll = (float*)alloc(768 * 4);
    float* bsc = (float*)alloc(128 * 4);
    float* bsh = (float*)alloc(128 * 4);
    int* gcnt = (int*)alloc((size_t)G_ * 4);
    int* goff = (int*)alloc((size_t)G_ * 4);
    float* pooled = (float*)alloc((size_t)G_ * HDIM * 4);
    float* psc = (float*)alloc(128 * 4);
    float* psh = (float*)alloc(128 * 4);
    float* z1 = (float*)alloc((size_t)G_ * HDIM * 4);

    // wconv layout (element offsets)
    const int oW = 0;
    const int oB = 49152;
    const int oLB1 = oB + 1408;
    const int oLW1 = oLB1 + 128;
    const int oLW2 = oLW1 + 16384;
    const int oLB2 = oLW2 + 1280;

    init_all<<<3, 256, 0, stream>>>((const unsigned int*)x, (const unsigned int*)ei, flags,
                                    gsumAll);

    ParamTab tab;
    const int srcIdx[18] = {3, 7, 11, 4, 5, 6, 8, 9, 10, 12, 13, 14, 15, 16, 18, 17, 19, 20};
    const int dstOff[18] = {oW, oW + 16384, oW + 32768,
                            oB + 0, oB + 128, oB + 256,
                            oB + 384, oB + 512, oB + 640,
                            oB + 768, oB + 896, oB + 1024,
                            oB + 1152, oB + 1280,
                            oLB1, oLW1, oLW2, oLB2};
    for (int i = 0; i < 18; i++) {
        tab.p[i] = d_in[srcIdx[i]];
        tab.n[i] = in_sizes[srcIdx[i]];
        tab.off[i] = dstOff[i];
    }
    convert_params<<<18, 256, 0, stream>>>(tab, wconv, flags);

    // CSR build: bucket sort
    p1_hist<<<ntiles, 256, 0, stream>>>(ei, flags, Ct, E_, NB, ntiles);
    scanA<<<nscan, 256, 0, stream>>>(Ct, part, L);
    scan2<<<1, 128, 0, stream>>>(part, nscan);
    scanC<<<nscan, 256, 0, stream>>>(Ct, part, L);
    p1_scatter<<<ntiles, 256, 0, stream>>>(ei, flags, Ct, pairs, E_, NB, ntiles);
    p2_build<<<NB, 256, 0, stream>>>(pairs, Ct, csrc, offs, cnt, dis, E_, N_, NB, ntiles);

    gbounds<<<(G_ + 255) / 256, 256, 0, stream>>>(batch, flags, goff, gcnt, N_, G_);

    repack<<<(3 * 2048 + 255) / 256, 256, 0, stream>>>(wconv, wfrag);

    int mm_blocks = (((N_ + 15) / 16) * 64 + 255) / 256;
    int agg_blocks = (N_ + 15) / 16;  // 4 nodes/wave, 4 waves/block
    float invn = 1.f / (float)N_;

    for (int l = 0; l < 3; l++) {
        const void* A = (l == 0) ? x : (const void*)aggbuf;
        mm_mfma<<<mm_blocks, 256, 0, stream>>>(A, wfrag + (size_t)l * HDIM * HDIM, hw, N_,
                                               bsc, bsh, dis, flags, (l == 0) ? 1 : 0);
        aggregate<<<agg_blocks, 256, 0, stream>>>(hw, dis, offs, cnt, csrc,
                                                  wconv + oB + l * 384, aggbuf, N_);
        float* gsum = gsumAll + l * 256;
        col_stats<<<512, 256, 0, stream>>>(aggbuf, gsum, gsum + 128, N_);
        bn_finalize<<<1, 128, 0, stream>>>(gsum, gsum + 128, wconv + oB + l * 384 + 128,
                                           wconv + oB + l * 384 + 256, bsc, bsh, invn);
    }

    pool<<<G_, 256, 0, stream>>>(aggbuf, goff, gcnt, bsc, bsh, pooled);
    pooled_bn<<<1, 512, 0, stream>>>(pooled, wconv + oB + 1152, wconv + oB + 1280, psc, psh, G_);
    mlp1<<<G_, 128, 0, stream>>>(pooled, psc, psh, wconv + oLW1, wconv + oLB1, z1);
    mlp2<<<G_, 128, 0, stream>>>(z1, wconv + oLW2, wconv + oLB2, d_out, flags);
}

// Round 6
// 612.764 us; speedup vs baseline: 2.0520x; 1.0765x over previous
//
#include <hip/hip_runtime.h>
#include <hip/hip_bf16.h>
#include <cstdint>

#define HDIM 128

typedef __bf16 bf16x8 __attribute__((ext_vector_type(8)));
typedef unsigned short usx8 __attribute__((ext_vector_type(8)));
typedef float fx4 __attribute__((ext_vector_type(4)));

__device__ __forceinline__ float bf2f(unsigned short u) {
    unsigned int x = ((unsigned int)u) << 16;
    return __uint_as_float(x);
}
__device__ __forceinline__ unsigned short f2bf(float f) {
    unsigned int x = __float_as_uint(f);
    x += 0x7fffu + ((x >> 16) & 1u);
    return (unsigned short)(x >> 16);
}

// detect dtypes from raw words (run per-block to avoid cross-block deps)
__device__ __forceinline__ void detect_local(const unsigned int* xw, const unsigned int* eiw,
                                             int& f0, int& f1) {
    int sane = 0;
    for (int k = 0; k < 64; k++) {
        unsigned int w = xw[k];
        unsigned short ss[2] = {(unsigned short)(w & 0xffffu), (unsigned short)(w >> 16)};
        for (int q = 0; q < 2; q++) {
            int e = (ss[q] >> 7) & 0xFF;
            if ((ss[q] & 0x7fffu) == 0 || (e >= 100 && e <= 140)) sane++;
        }
    }
    f0 = (sane >= 110) ? 1 : 0;
    int zeros = 0;
    for (int k = 1; k < 64; k += 2)
        if (eiw[k] == 0) zeros++;
    f1 = (zeros >= 24) ? 1 : 0;
}

struct ParamTab {
    const void* p[15];
    int n[15];
    int off[15];
};

// ---------------- phase1: hist + param-convert + gbounds + repack + init ----------------
__global__ void phase1(const unsigned int* __restrict__ xw, const unsigned int* __restrict__ eiw,
                       const void* __restrict__ ei, const void* __restrict__ batch,
                       const void* __restrict__ W1, const void* __restrict__ W2,
                       const void* __restrict__ W3, ParamTab tab, int* __restrict__ flags,
                       float* __restrict__ gsumAll, int* __restrict__ Ct,
                       unsigned short* __restrict__ wconv, unsigned short* __restrict__ Wf,
                       int* __restrict__ goff, int* __restrict__ gcnt, int E, int N, int G,
                       int NB, int ntiles, int TILE) {
    __shared__ int h[1024];
    __shared__ int lf0s, lf1s;
    int b = blockIdx.x, t = threadIdx.x;
    if (t == 0) {
        int a0, a1;
        detect_local(xw, eiw, a0, a1);
        lf0s = a0;
        lf1s = a1;
    }
    __syncthreads();
    int lf0 = lf0s, lf1 = lf1s;
    if (b < ntiles) {
        for (int i = t; i < NB; i += 256) h[i] = 0;
        __syncthreads();
        int base = b * TILE;
        for (int i = t; i < TILE; i += 256) {
            int idx = base + i;
            if (idx < E) {
                int d = lf1 ? (int)((const long long*)ei)[(size_t)E + idx]
                            : ((const int*)ei)[(size_t)E + idx];
                atomicAdd(&h[d >> 9], 1);
            }
        }
        __syncthreads();
        for (int k = t; k < NB; k += 256) Ct[k * ntiles + b] = h[k];
    } else if (b < ntiles + 15) {
        int pb = b - ntiles;
        const void* src = tab.p[pb];
        int n = tab.n[pb];
        unsigned short* o = wconv + tab.off[pb];
        if (lf0) {
            const unsigned short* s = (const unsigned short*)src;
            for (int i = t; i < n; i += 256) o[i] = s[i];
        } else {
            const float* s = (const float*)src;
            for (int i = t; i < n; i += 256) o[i] = f2bf(s[i]);
        }
    } else if (b < ntiles + 17) {
        int gi = (b - ntiles - 15) * 256 + t;
        if (gi < G) {
            auto getb = [&](int i) -> int {
                return lf1 ? (int)((const long long*)batch)[i] : ((const int*)batch)[i];
            };
            auto lower = [&](int val) -> int {
                int lo = 0, hi = N;
                while (lo < hi) {
                    int mid = (lo + hi) >> 1;
                    if (getb(mid) < val) lo = mid + 1;
                    else hi = mid;
                }
                return lo;
            };
            int lo = lower(gi), hi = lower(gi + 1);
            goff[gi] = lo;
            gcnt[gi] = hi - lo;
        }
    } else if (b < ntiles + 17 + 24) {
        int idx = (b - ntiles - 17) * 256 + t;  // 0..6143
        int layer = idx >> 11;
        int rem = idx & 2047;
        int kt = rem >> 9;
        int nt = (rem >> 6) & 7;
        int lane = rem & 63;
        const void* W = (layer == 0) ? W1 : ((layer == 1) ? W2 : W3);
        int row = lane & 15, quad = lane >> 4;
        unsigned short* o = Wf + ((size_t)layer * 2048 + (size_t)((kt * 8 + nt) * 64 + lane)) * 8;
#pragma unroll
        for (int j = 0; j < 8; j++) {
            int k = kt * 32 + quad * 8 + j;
            int off = k * HDIM + nt * 16 + row;
            o[j] = lf0 ? ((const unsigned short*)W)[off] : f2bf(((const float*)W)[off]);
        }
    } else {
        for (int i = t; i < 768; i += 256) gsumAll[i] = 0.f;
        if (t == 0) {
            flags[0] = lf0;
            flags[1] = lf1;
        }
    }
}

// ---------------- scans over Ct ----------------
__global__ void scanA(const int* __restrict__ d, int* __restrict__ part, int L) {
    __shared__ int ls[256];
    int b = blockIdx.x, t = threadIdx.x;
    int base = b * 2048;
    int s = 0;
    for (int j = t; j < 2048; j += 256) {
        int i = base + j;
        if (i < L) s += d[i];
    }
    ls[t] = s;
    __syncthreads();
    for (int o = 128; o > 0; o >>= 1) {
        if (t < o) ls[t] += ls[t + o];
        __syncthreads();
    }
    if (t == 0) part[b] = ls[0];
}
__global__ void scan2(int* part, int nb) {
    __shared__ int ls[128];
    int t = threadIdx.x;
    int orig = (t < nb) ? part[t] : 0;
    ls[t] = orig;
    __syncthreads();
    for (int o = 1; o < 128; o <<= 1) {
        int v = (t >= o) ? ls[t - o] : 0;
        __syncthreads();
        ls[t] += v;
        __syncthreads();
    }
    if (t < nb) part[t] = ls[t] - orig;  // exclusive
}
__global__ void scanC(int* __restrict__ d, const int* __restrict__ part, int L) {
    __shared__ int ls[256];
    __shared__ int excl[256];
    int b = blockIdx.x, t = threadIdx.x;
    int i0 = b * 2048 + t * 8;
    int v[8];
    int s = 0;
#pragma unroll
    for (int q = 0; q < 8; q++) {
        v[q] = (i0 + q < L) ? d[i0 + q] : 0;
        s += v[q];
    }
    ls[t] = s;
    __syncthreads();
    if (t == 0) {
        int a = 0;
        for (int j = 0; j < 256; j++) { excl[j] = a; a += ls[j]; }
    }
    __syncthreads();
    int base = part[b] + excl[t];
#pragma unroll
    for (int q = 0; q < 8; q++) {
        if (i0 + q < L) d[i0 + q] = base;
        base += v[q];
    }
}

// ---------------- scatter to bucket-contiguous packed pairs ----------------
__global__ void p1_scatter(const void* __restrict__ ei, const int* __restrict__ flags,
                           const int* __restrict__ Ct, unsigned int* __restrict__ pairs, int E,
                           int NB, int ntiles, int TILE) {
    __shared__ int cur[1024];
    int tile = blockIdx.x, t = threadIdx.x;
    for (int i = t; i < NB; i += 256) cur[i] = Ct[i * ntiles + tile];
    __syncthreads();
    int base = tile * TILE;
    bool i64 = flags[1] != 0;
    for (int i = t; i < TILE; i += 256) {
        int idx = base + i;
        if (idx < E) {
            int s, d;
            if (i64) {
                s = (int)((const long long*)ei)[idx];
                d = (int)((const long long*)ei)[(size_t)E + idx];
            } else {
                s = ((const int*)ei)[idx];
                d = ((const int*)ei)[(size_t)E + idx];
            }
            int pos = atomicAdd(&cur[d >> 9], 1);
            pairs[pos] = ((unsigned)(d & 511) << 23) | (unsigned)s;
        }
    }
}

// ---------------- per-bucket: group by node, emit csrc/offs/cnt/dis ----------------
__global__ void p2_build(const unsigned int* __restrict__ pairs, const int* __restrict__ Ct,
                         int* __restrict__ csrc, int* __restrict__ offs, int* __restrict__ cnt,
                         float* __restrict__ dis, int E, int N, int NB, int ntiles) {
    __shared__ int hist[512];
    __shared__ int start[512];
    __shared__ int cur[512];
    __shared__ int ps[256];
    int b = blockIdx.x, t = threadIdx.x;
    int node0 = b * 512;
    for (int i = t; i < 512; i += 256) hist[i] = 0;
    __syncthreads();
    int lo = Ct[b * ntiles];
    int hi = (b + 1 < NB) ? Ct[(b + 1) * ntiles] : E;
    for (int i = lo + t; i < hi; i += 256) {
        atomicAdd(&hist[pairs[i] >> 23], 1);
    }
    __syncthreads();
    ps[t] = hist[2 * t] + hist[2 * t + 1];
    __syncthreads();
    for (int o = 1; o < 256; o <<= 1) {
        int v = (t >= o) ? ps[t - o] : 0;
        __syncthreads();
        ps[t] += v;
        __syncthreads();
    }
    int e = t ? ps[t - 1] : 0;
    start[2 * t] = e;
    start[2 * t + 1] = e + hist[2 * t];
    __syncthreads();
    for (int i = t; i < 512; i += 256) {
        cur[i] = 0;
        int node = node0 + i;
        if (node < N) {
            offs[node] = lo + start[i];
            cnt[node] = hist[i];
            dis[node] = rsqrtf((float)(hist[i] + 1));
        }
    }
    __syncthreads();
    for (int i = lo + t; i < hi; i += 256) {
        unsigned int p = pairs[i];
        int l = p >> 23;
        int pos = lo + start[l] + atomicAdd(&cur[l], 1);
        csrc[pos] = (int)(p & 0x7fffffu);
    }
}

// ---------------- GEMM: C[m,:] = dis[m] * (pre(A)[m,:] @ W), bf16 MFMA ----------------
__global__ __launch_bounds__(256) void mm_mfma(const void* __restrict__ A,
                                               const unsigned short* __restrict__ Wf,
                                               unsigned short* __restrict__ C, int M,
                                               const float* __restrict__ sc,
                                               const float* __restrict__ sh,
                                               const float* __restrict__ dis,
                                               const int* __restrict__ flags, int l0mode) {
    int gid = blockIdx.x * blockDim.x + threadIdx.x;
    int wave = gid >> 6;
    int lane = threadIdx.x & 63;
    int m0 = wave * 16;
    if (m0 >= M) return;
    int row = lane & 15, quad = lane >> 4;
    bool xfp32 = l0mode && !flags[0];
    const unsigned short* arow =
        (const unsigned short*)A + (size_t)(m0 + row) * HDIM + quad * 8;
    const float* arowf = (const float*)A + (size_t)(m0 + row) * HDIM + quad * 8;
    fx4 acc[8];
#pragma unroll
    for (int t = 0; t < 8; t++) acc[t] = (fx4){0.f, 0.f, 0.f, 0.f};
#pragma unroll
    for (int kt = 0; kt < 4; kt++) {
        bf16x8 a;
        if (xfp32) {
            fx4 f0 = *(const fx4*)(arowf + kt * 32);
            fx4 f1 = *(const fx4*)(arowf + kt * 32 + 4);
            usx8 t;
#pragma unroll
            for (int q = 0; q < 4; q++) t[q] = f2bf(f0[q]);
#pragma unroll
            for (int q = 0; q < 4; q++) t[4 + q] = f2bf(f1[q]);
            a = __builtin_bit_cast(bf16x8, t);
        } else {
            usx8 raw = *(const usx8*)(arow + kt * 32);
            if (!l0mode) {
                int col = kt * 32 + quad * 8;
                fx4 s0 = *(const fx4*)(sc + col);
                fx4 s1 = *(const fx4*)(sc + col + 4);
                fx4 h0 = *(const fx4*)(sh + col);
                fx4 h1 = *(const fx4*)(sh + col + 4);
                usx8 t;
#pragma unroll
                for (int q = 0; q < 4; q++)
                    t[q] = f2bf(fmaxf(s0[q] * bf2f(raw[q]) + h0[q], 0.f));
#pragma unroll
                for (int q = 0; q < 4; q++)
                    t[4 + q] = f2bf(fmaxf(s1[q] * bf2f(raw[4 + q]) + h1[q], 0.f));
                a = __builtin_bit_cast(bf16x8, t);
            } else {
                a = __builtin_bit_cast(bf16x8, raw);
            }
        }
        const unsigned short* wf = Wf + ((size_t)(kt * 8) * 64 + lane) * 8;
#pragma unroll
        for (int nt = 0; nt < 8; nt++) {
            bf16x8 b = __builtin_bit_cast(bf16x8, *(const usx8*)(wf + (size_t)nt * 64 * 8));
            acc[nt] = __builtin_amdgcn_mfma_f32_16x16x32_bf16(a, b, acc[nt], 0, 0, 0);
        }
    }
    float dsc[4];
#pragma unroll
    for (int r = 0; r < 4; r++) dsc[r] = dis[m0 + quad * 4 + r];
#pragma unroll
    for (int nt = 0; nt < 8; nt++) {
        int col = nt * 16 + row;
#pragma unroll
        for (int r = 0; r < 4; r++) {
            int m = m0 + quad * 4 + r;
            C[(size_t)m * HDIM + col] = f2bf(acc[nt][r] * dsc[r]);
        }
    }
}

// ---------------- aggregation: 4 nodes/wave, 2-deep row-load unroll ----------------
__global__ __launch_bounds__(256) void aggregate(const unsigned short* __restrict__ hw,
                                                 const float* __restrict__ dis,
                                                 const int* __restrict__ offs,
                                                 const int* __restrict__ cnt,
                                                 const int* __restrict__ csrc,
                                                 const unsigned short* __restrict__ bias,
                                                 unsigned short* __restrict__ agg, int n) {
    int wv = (blockIdx.x * blockDim.x + threadIdx.x) >> 6;
    int lane = threadIdx.x & 63;
    int grp = lane >> 4, sub = lane & 15;
    int node = wv * 4 + grp;
    if (node >= n) return;
    int colb = sub * 8;
    usx8 sv = *(const usx8*)(hw + (size_t)node * HDIM + colb);
    float a[8];
#pragma unroll
    for (int q = 0; q < 8; q++) a[q] = bf2f(sv[q]);
    int o = offs[node], c = cnt[node];
    int s0 = (c > 0) ? csrc[o] : 0;
    int s1 = (c > 1) ? csrc[o + 1] : 0;
    int j = 0;
    while (j < c) {
        usx8 v0 = *(const usx8*)(hw + (size_t)s0 * HDIM + colb);
        usx8 v1 = *(const usx8*)(hw + (size_t)s1 * HDIM + colb);
        int s2 = (j + 2 < c) ? csrc[o + j + 2] : 0;
        int s3 = (j + 3 < c) ? csrc[o + j + 3] : 0;
#pragma unroll
        for (int q = 0; q < 8; q++) a[q] += bf2f(v0[q]);
        if (j + 1 < c) {
#pragma unroll
            for (int q = 0; q < 8; q++) a[q] += bf2f(v1[q]);
        }
        s0 = s2;
        s1 = s3;
        j += 2;
    }
    float di = dis[node];
    usx8 bv = *(const usx8*)(bias + colb);
    usx8 ov;
#pragma unroll
    for (int q = 0; q < 8; q++) ov[q] = f2bf(bf2f(bv[q]) + di * a[q]);
    *(usx8*)(agg + (size_t)node * HDIM + colb) = ov;
}

// ---------------- BN stats / finalize ----------------
__global__ void col_stats(const unsigned short* __restrict__ agg, float* __restrict__ gsum,
                          float* __restrict__ gsq, int n) {
    int t = threadIdx.x;
    int c = t & 127, p = t >> 7;
    float s = 0.f, s2 = 0.f;
    int stride = gridDim.x * 2;
    for (int r = blockIdx.x * 2 + p; r < n; r += stride) {
        float v = bf2f(agg[(size_t)r * HDIM + c]);
        s += v;
        s2 += v * v;
    }
    __shared__ float ls[256], ls2[256];
    ls[t] = s;
    ls2[t] = s2;
    __syncthreads();
    if (t < 128) {
        atomicAdd(&gsum[t], ls[t] + ls[t + 128]);
        atomicAdd(&gsq[t], ls2[t] + ls2[t + 128]);
    }
}
__global__ void bn_finalize(const float* __restrict__ gsum, const float* __restrict__ gsq,
                            const unsigned short* __restrict__ g,
                            const unsigned short* __restrict__ be,
                            float* __restrict__ sc, float* __restrict__ sh, float invn) {
    int c = threadIdx.x;
    if (c < 128) {
        float m = gsum[c] * invn;
        float v = gsq[c] * invn - m * m;
        float s = bf2f(g[c]) * rsqrtf(v + 1e-5f);
        sc[c] = s;
        sh[c] = bf2f(be[c]) - m * s;
    }
}

// ---------------- pooling (fused BN3+ReLU) + head ----------------
__global__ void pool(const unsigned short* __restrict__ hin, const int* __restrict__ goff,
                     const int* __restrict__ gcnt, const float* __restrict__ sc,
                     const float* __restrict__ sh, float* __restrict__ pooled) {
    int g = blockIdx.x, t = threadIdx.x;
    int c = t & 127, p = t >> 7;
    float scale = sc[c], shift = sh[c];
    int s = goff[g], cn = gcnt[g];
    float acc = 0.f;
    for (int r = s + p; r < s + cn; r += 2)
        acc += fmaxf(scale * bf2f(hin[(size_t)r * HDIM + c]) + shift, 0.f);
    __shared__ float ls[256];
    ls[t] = acc;
    __syncthreads();
    if (t < 128) pooled[(size_t)g * HDIM + t] = (ls[t] + ls[t + 128]) / fmaxf((float)cn, 1.f);
}
__global__ void pooled_bn(const float* __restrict__ pooled, const unsigned short* __restrict__ g,
                          const unsigned short* __restrict__ be, float* __restrict__ psc,
                          float* __restrict__ psh, int G_) {
    int t = threadIdx.x;
    int c = t & 127, p = t >> 7;
    float s = 0.f, s2 = 0.f;
    for (int r = p; r < G_; r += 4) {
        float v = pooled[(size_t)r * HDIM + c];
        s += v;
        s2 += v * v;
    }
    __shared__ float ls[512], ls2[512];
    ls[t] = s;
    ls2[t] = s2;
    __syncthreads();
    if (t < 128) {
        float S = ls[t] + ls[t + 128] + ls[t + 256] + ls[t + 384];
        float S2 = ls2[t] + ls2[t + 128] + ls2[t + 256] + ls2[t + 384];
        float m = S / (float)G_;
        float v = S2 / (float)G_ - m * m;
        float sc = bf2f(g[t]) * rsqrtf(v + 1e-5f);
        psc[t] = sc;
        psh[t] = bf2f(be[t]) - m * sc;
    }
}
__global__ void mlp1(const float* __restrict__ pooled, const float* __restrict__ psc,
                     const float* __restrict__ psh, const unsigned short* __restrict__ lw1,
                     const unsigned short* __restrict__ lb1, float* __restrict__ z1) {
    int r = blockIdx.x, t = threadIdx.x;
    __shared__ float row[128];
    row[t] = psc[t] * pooled[(size_t)r * HDIM + t] + psh[t];
    __syncthreads();
    float acc = bf2f(lb1[t]);
    for (int k = 0; k < 128; k++) acc += row[k] * bf2f(lw1[k * HDIM + t]);
    z1[(size_t)r * HDIM + t] = fmaxf(acc, 0.f);
}
__global__ void mlp2(const float* __restrict__ z1, const unsigned short* __restrict__ lw2,
                     const unsigned short* __restrict__ lb2, void* __restrict__ out,
                     const int* __restrict__ flags) {
    int r = blockIdx.x, t = threadIdx.x;
    __shared__ float row[128];
    __shared__ float z2[10];
    __shared__ float lse;
    row[t] = z1[(size_t)r * HDIM + t];
    __syncthreads();
    if (t < 10) {
        float a = bf2f(lb2[t]);
        for (int k = 0; k < 128; k++) a += row[k] * bf2f(lw2[k * 10 + t]);
        z2[t] = a;
    }
    __syncthreads();
    if (t == 0) {
        float m = z2[0];
        for (int j = 1; j < 10; j++) m = fmaxf(m, z2[j]);
        float s = 0.f;
        for (int j = 0; j < 10; j++) s += expf(z2[j] - m);
        lse = m + logf(s);
    }
    __syncthreads();
    if (t < 10) {
        float v = z2[t] - lse;
        if (flags[0]) ((unsigned short*)out)[r * 10 + t] = f2bf(v);
        else ((float*)out)[r * 10 + t] = v;
    }
}

extern "C" void kernel_launch(void* const* d_in, const int* in_sizes, int n_in,
                              void* d_out, int out_size, void* d_ws, size_t ws_size,
                              hipStream_t stream) {
    const void* x = d_in[0];
    const void* ei = d_in[1];
    const void* batch = d_in[2];

    int N_ = in_sizes[2];
    int E_ = in_sizes[1] / 2;
    int G_ = out_size / 10;

    const int TILE = 4096;
    int NB = (N_ + 511) / 512;
    int ntiles = (E_ + TILE - 1) / TILE;
    int L = NB * ntiles;
    int nscan = (L + 2047) / 2048;

    char* ws = (char*)d_ws;
    auto alloc = [&](size_t bytes) -> char* {
        char* p = ws;
        ws += (bytes + 255) & ~(size_t)255;
        return p;
    };
    int* flags = (int*)alloc(256);
    float* dis = (float*)alloc((size_t)N_ * 4);
    int* offs = (int*)alloc((size_t)N_ * 4);
    int* cnt = (int*)alloc((size_t)N_ * 4);
    int* part = (int*)alloc(4096);
    int* Ct = (int*)alloc((size_t)L * 4);
    unsigned int* pairs = (unsigned int*)alloc((size_t)E_ * 4);
    int* csrc = (int*)alloc((size_t)E_ * 4);
    unsigned short* hw = (unsigned short*)alloc((size_t)N_ * HDIM * 2);
    unsigned short* aggbuf = (unsigned short*)alloc((size_t)N_ * HDIM * 2);
    unsigned short* wconv = (unsigned short*)alloc(70000 * 2);
    unsigned short* wfrag = (unsigned short*)alloc(3 * HDIM * HDIM * 2);
    float* gsumAll = (float*)alloc(768 * 4);
    float* bsc = (float*)alloc(128 * 4);
    float* bsh = (float*)alloc(128 * 4);
    int* gcnt = (int*)alloc((size_t)G_ * 4);
    int* goff = (int*)alloc((size_t)G_ * 4);
    float* pooled = (float*)alloc((size_t)G_ * HDIM * 4);
    float* psc = (float*)alloc(128 * 4);
    float* psh = (float*)alloc(128 * 4);
    float* z1 = (float*)alloc((size_t)G_ * HDIM * 4);

    // wconv layout (element offsets) — W region unused (repack reads raw)
    const int oB = 49152;
    const int oLB1 = oB + 1408;
    const int oLW1 = oLB1 + 128;
    const int oLW2 = oLW1 + 16384;
    const int oLB2 = oLW2 + 1280;

    ParamTab tab;
    const int srcIdx[15] = {4, 5, 6, 8, 9, 10, 12, 13, 14, 15, 16, 18, 17, 19, 20};
    const int dstOff[15] = {oB + 0, oB + 128, oB + 256,
                            oB + 384, oB + 512, oB + 640,
                            oB + 768, oB + 896, oB + 1024,
                            oB + 1152, oB + 1280,
                            oLB1, oLW1, oLW2, oLB2};
    for (int i = 0; i < 15; i++) {
        tab.p[i] = d_in[srcIdx[i]];
        tab.n[i] = in_sizes[srcIdx[i]];
        tab.off[i] = dstOff[i];
    }

    int gb = (G_ + 255) / 256;  // must be <= 2 for role mapping (G=512)
    int p1_grid = ntiles + 15 + 2 + 24 + 1;
    phase1<<<p1_grid, 256, 0, stream>>>((const unsigned int*)x, (const unsigned int*)ei, ei,
                                        batch, d_in[3], d_in[7], d_in[11], tab, flags, gsumAll,
                                        Ct, wconv, wfrag, goff, gcnt, E_, N_, G_, NB, ntiles,
                                        TILE);
    (void)gb;

    scanA<<<nscan, 256, 0, stream>>>(Ct, part, L);
    scan2<<<1, 128, 0, stream>>>(part, nscan);
    scanC<<<nscan, 256, 0, stream>>>(Ct, part, L);
    p1_scatter<<<ntiles, 256, 0, stream>>>(ei, flags, Ct, pairs, E_, NB, ntiles, TILE);
    p2_build<<<NB, 256, 0, stream>>>(pairs, Ct, csrc, offs, cnt, dis, E_, N_, NB, ntiles);

    int mm_blocks = (((N_ + 15) / 16) * 64 + 255) / 256;
    int agg_blocks = (N_ + 15) / 16;  // 4 nodes/wave, 4 waves/block
    float invn = 1.f / (float)N_;

    for (int l = 0; l < 3; l++) {
        const void* A = (l == 0) ? x : (const void*)aggbuf;
        mm_mfma<<<mm_blocks, 256, 0, stream>>>(A, wfrag + (size_t)l * HDIM * HDIM, hw, N_,
                                               bsc, bsh, dis, flags, (l == 0) ? 1 : 0);
        aggregate<<<agg_blocks, 256, 0, stream>>>(hw, dis, offs, cnt, csrc,
                                                  wconv + oB + l * 384, aggbuf, N_);
        float* gsum = gsumAll + l * 256;
        col_stats<<<512, 256, 0, stream>>>(aggbuf, gsum, gsum + 128, N_);
        bn_finalize<<<1, 128, 0, stream>>>(gsum, gsum + 128, wconv + oB + l * 384 + 128,
                                           wconv + oB + l * 384 + 256, bsc, bsh, invn);
    }

    pool<<<G_, 256, 0, stream>>>(aggbuf, goff, gcnt, bsc, bsh, pooled);
    pooled_bn<<<1, 512, 0, stream>>>(pooled, wconv + oB + 1152, wconv + oB + 1280, psc, psh, G_);
    mlp1<<<G_, 128, 0, stream>>>(pooled, psc, psh, wconv + oLW1, wconv + oLB1, z1);
    mlp2<<<G_, 128, 0, stream>>>(z1, wconv + oLW2, wconv + oLB2, d_out, flags);
}

// Round 7
// 514.475 us; speedup vs baseline: 2.4441x; 1.1910x over previous
//
#include <hip/hip_runtime.h>
#include <hip/hip_bf16.h>
#include <cstdint>

#define HDIM 128

typedef __bf16 bf16x8 __attribute__((ext_vector_type(8)));
typedef unsigned short usx8 __attribute__((ext_vector_type(8)));
typedef float fx4 __attribute__((ext_vector_type(4)));

__device__ __forceinline__ float bf2f(unsigned short u) {
    unsigned int x = ((unsigned int)u) << 16;
    return __uint_as_float(x);
}
__device__ __forceinline__ unsigned short f2bf(float f) {
    unsigned int x = __float_as_uint(f);
    x += 0x7fffu + ((x >> 16) & 1u);
    return (unsigned short)(x >> 16);
}

__device__ __forceinline__ void detect_local(const unsigned int* xw, const unsigned int* eiw,
                                             int& f0, int& f1) {
    int sane = 0;
    for (int k = 0; k < 64; k++) {
        unsigned int w = xw[k];
        unsigned short ss[2] = {(unsigned short)(w & 0xffffu), (unsigned short)(w >> 16)};
        for (int q = 0; q < 2; q++) {
            int e = (ss[q] >> 7) & 0xFF;
            if ((ss[q] & 0x7fffu) == 0 || (e >= 100 && e <= 140)) sane++;
        }
    }
    f0 = (sane >= 110) ? 1 : 0;
    int zeros = 0;
    for (int k = 1; k < 64; k += 2)
        if (eiw[k] == 0) zeros++;
    f1 = (zeros >= 24) ? 1 : 0;
}

struct ParamTab {
    const void* p[15];
    int n[15];
    int off[15];
};

// ---------------- phase1: hist + param-convert + gbounds + repack + init ----------------
__global__ void phase1(const unsigned int* __restrict__ xw, const unsigned int* __restrict__ eiw,
                       const void* __restrict__ ei, const void* __restrict__ batch,
                       const void* __restrict__ W1, const void* __restrict__ W2,
                       const void* __restrict__ W3, ParamTab tab, int* __restrict__ flags,
                       float* __restrict__ gsumAll, int* __restrict__ Ct,
                       unsigned short* __restrict__ wconv, unsigned short* __restrict__ Wf,
                       int* __restrict__ goff, int* __restrict__ gcnt, int E, int N, int G,
                       int NB, int ntiles, int TILE) {
    __shared__ int h[1024];
    __shared__ int lf0s, lf1s;
    int b = blockIdx.x, t = threadIdx.x;
    if (t == 0) {
        int a0, a1;
        detect_local(xw, eiw, a0, a1);
        lf0s = a0;
        lf1s = a1;
    }
    __syncthreads();
    int lf0 = lf0s, lf1 = lf1s;
    if (b < ntiles) {
        for (int i = t; i < NB; i += 256) h[i] = 0;
        __syncthreads();
        int base = b * TILE;
        for (int i = t; i < TILE; i += 256) {
            int idx = base + i;
            if (idx < E) {
                int d = lf1 ? (int)((const long long*)ei)[(size_t)E + idx]
                            : ((const int*)ei)[(size_t)E + idx];
                atomicAdd(&h[d >> 9], 1);
            }
        }
        __syncthreads();
        for (int k = t; k < NB; k += 256) Ct[k * ntiles + b] = h[k];
    } else if (b < ntiles + 15) {
        int pb = b - ntiles;
        const void* src = tab.p[pb];
        int n = tab.n[pb];
        unsigned short* o = wconv + tab.off[pb];
        if (lf0) {
            const unsigned short* s = (const unsigned short*)src;
            for (int i = t; i < n; i += 256) o[i] = s[i];
        } else {
            const float* s = (const float*)src;
            for (int i = t; i < n; i += 256) o[i] = f2bf(s[i]);
        }
    } else if (b < ntiles + 17) {
        int gi = (b - ntiles - 15) * 256 + t;
        if (gi < G) {
            auto getb = [&](int i) -> int {
                return lf1 ? (int)((const long long*)batch)[i] : ((const int*)batch)[i];
            };
            auto lower = [&](int val) -> int {
                int lo = 0, hi = N;
                while (lo < hi) {
                    int mid = (lo + hi) >> 1;
                    if (getb(mid) < val) lo = mid + 1;
                    else hi = mid;
                }
                return lo;
            };
            int lo = lower(gi), hi = lower(gi + 1);
            goff[gi] = lo;
            gcnt[gi] = hi - lo;
        }
    } else if (b < ntiles + 17 + 24) {
        int idx = (b - ntiles - 17) * 256 + t;  // 0..6143
        int layer = idx >> 11;
        int rem = idx & 2047;
        int kt = rem >> 9;
        int nt = (rem >> 6) & 7;
        int lane = rem & 63;
        const void* W = (layer == 0) ? W1 : ((layer == 1) ? W2 : W3);
        int row = lane & 15, quad = lane >> 4;
        unsigned short* o = Wf + ((size_t)layer * 2048 + (size_t)((kt * 8 + nt) * 64 + lane)) * 8;
#pragma unroll
        for (int j = 0; j < 8; j++) {
            int k = kt * 32 + quad * 8 + j;
            int off = k * HDIM + nt * 16 + row;
            o[j] = lf0 ? ((const unsigned short*)W)[off] : f2bf(((const float*)W)[off]);
        }
    } else {
        for (int i = t; i < 6144; i += 256) gsumAll[i] = 0.f;
        if (t == 0) {
            flags[0] = lf0;
            flags[1] = lf1;
        }
    }
}

// ---------------- per-bucket scan over its tile counts (512 threads; ntiles<=512) ---------
__global__ void s1_scan(int* __restrict__ Ct, int* __restrict__ btot, int NB, int ntiles) {
    __shared__ int buf[512];
    int b = blockIdx.x, t = threadIdx.x;
    int v = (t < ntiles) ? Ct[b * ntiles + t] : 0;
    buf[t] = v;
    __syncthreads();
    for (int o = 1; o < 512; o <<= 1) {
        int a = (t >= o) ? buf[t - o] : 0;
        __syncthreads();
        buf[t] += a;
        __syncthreads();
    }
    if (t < ntiles) Ct[b * ntiles + t] = buf[t] - v;  // exclusive within bucket
    if (t == 0) btot[b] = buf[511];
}

// ---------------- scatter to bucket-contiguous packed pairs ----------------
__global__ void p1_scatter(const void* __restrict__ ei, const int* __restrict__ flags,
                           const int* __restrict__ Ct, const int* __restrict__ btot,
                           unsigned int* __restrict__ pairs, int E, int NB, int ntiles,
                           int TILE) {
    __shared__ int cur[1024];
    __shared__ int bb[256];
    int tile = blockIdx.x, t = threadIdx.x;
    int v = (t < NB) ? btot[t] : 0;
    bb[t] = v;
    __syncthreads();
    for (int o = 1; o < 256; o <<= 1) {
        int a = (t >= o) ? bb[t - o] : 0;
        __syncthreads();
        bb[t] += a;
        __syncthreads();
    }
    if (t < NB) cur[t] = (bb[t] - v) + Ct[t * ntiles + tile];
    __syncthreads();
    int base = tile * TILE;
    bool i64 = flags[1] != 0;
    for (int i = t; i < TILE; i += 256) {
        int idx = base + i;
        if (idx < E) {
            int s, d;
            if (i64) {
                s = (int)((const long long*)ei)[idx];
                d = (int)((const long long*)ei)[(size_t)E + idx];
            } else {
                s = ((const int*)ei)[idx];
                d = ((const int*)ei)[(size_t)E + idx];
            }
            int pos = atomicAdd(&cur[d >> 9], 1);
            pairs[pos] = ((unsigned)(d & 511) << 23) | (unsigned)s;
        }
    }
}

// ---------------- per-bucket: group by node, emit csrc/offs/cnt/dis ----------------
__global__ void p2_build(const unsigned int* __restrict__ pairs, const int* __restrict__ btot,
                         int* __restrict__ csrc, int* __restrict__ offs, int* __restrict__ cnt,
                         float* __restrict__ dis, int E, int N, int NB) {
    __shared__ int hist[512];
    __shared__ int start[512];
    __shared__ int cur[512];
    __shared__ int ps[256];
    __shared__ int bb[256];
    __shared__ int sh_excl[256];
    int b = blockIdx.x, t = threadIdx.x;
    int node0 = b * 512;
    // bucket base via LDS scan of btot
    int v = (t < NB) ? btot[t] : 0;
    bb[t] = v;
    __syncthreads();
    for (int o = 1; o < 256; o <<= 1) {
        int a = (t >= o) ? bb[t - o] : 0;
        __syncthreads();
        bb[t] += a;
        __syncthreads();
    }
    sh_excl[t] = bb[t] - v;
    for (int i = t; i < 512; i += 256) hist[i] = 0;
    __syncthreads();
    int lo = sh_excl[b];
    int hi = lo + ((b < NB) ? btot[b] : 0);
    for (int i = lo + t; i < hi; i += 256) {
        atomicAdd(&hist[pairs[i] >> 23], 1);
    }
    __syncthreads();
    ps[t] = hist[2 * t] + hist[2 * t + 1];
    __syncthreads();
    for (int o = 1; o < 256; o <<= 1) {
        int a = (t >= o) ? ps[t - o] : 0;
        __syncthreads();
        ps[t] += a;
        __syncthreads();
    }
    int e = t ? ps[t - 1] : 0;
    start[2 * t] = e;
    start[2 * t + 1] = e + hist[2 * t];
    __syncthreads();
    for (int i = t; i < 512; i += 256) {
        cur[i] = 0;
        int node = node0 + i;
        if (node < N) {
            offs[node] = lo + start[i];
            cnt[node] = hist[i];
            dis[node] = rsqrtf((float)(hist[i] + 1));
        }
    }
    __syncthreads();
    for (int i = lo + t; i < hi; i += 256) {
        unsigned int p = pairs[i];
        int l = p >> 23;
        int pos = lo + start[l] + atomicAdd(&cur[l], 1);
        csrc[pos] = (int)(p & 0x7fffffu);
    }
}

// ---------------- GEMM: C[m,:] = dis[m] * (bnrelu(A)[m,:] @ W), bf16 MFMA ----------------
// gsumPrev: 8-replica sums for input BN (null for layer 0)
__global__ __launch_bounds__(256) void mm_mfma(const void* __restrict__ A,
                                               const unsigned short* __restrict__ Wf,
                                               unsigned short* __restrict__ C, int M,
                                               const float* __restrict__ gsumPrev,
                                               const unsigned short* __restrict__ gamma,
                                               const unsigned short* __restrict__ beta,
                                               const float* __restrict__ dis,
                                               const int* __restrict__ flags, int l0mode,
                                               float invn) {
    __shared__ float scs[128], shs[128];
    __shared__ unsigned short ldsC[4 * 16 * 136];
    int t = threadIdx.x;
    if (!l0mode && t < 128) {
        float s = 0.f, s2 = 0.f;
#pragma unroll
        for (int r = 0; r < 8; r++) {
            s += gsumPrev[r * 256 + t];
            s2 += gsumPrev[r * 256 + 128 + t];
        }
        float m = s * invn;
        float vv = s2 * invn - m * m;
        float sc = bf2f(gamma[t]) * rsqrtf(vv + 1e-5f);
        scs[t] = sc;
        shs[t] = bf2f(beta[t]) - m * sc;
    }
    __syncthreads();
    int gid = blockIdx.x * blockDim.x + t;
    int wave = gid >> 6;
    int lane = t & 63;
    int wv = t >> 6;
    int m0 = wave * 16;
    if (m0 >= M) return;
    int row = lane & 15, quad = lane >> 4;
    bool xfp32 = l0mode && !flags[0];
    const unsigned short* arow = (const unsigned short*)A + (size_t)(m0 + row) * HDIM + quad * 8;
    const float* arowf = (const float*)A + (size_t)(m0 + row) * HDIM + quad * 8;
    fx4 acc[8];
#pragma unroll
    for (int k = 0; k < 8; k++) acc[k] = (fx4){0.f, 0.f, 0.f, 0.f};
#pragma unroll
    for (int kt = 0; kt < 4; kt++) {
        bf16x8 a;
        if (xfp32) {
            fx4 f0 = *(const fx4*)(arowf + kt * 32);
            fx4 f1 = *(const fx4*)(arowf + kt * 32 + 4);
            usx8 tt;
#pragma unroll
            for (int q = 0; q < 4; q++) tt[q] = f2bf(f0[q]);
#pragma unroll
            for (int q = 0; q < 4; q++) tt[4 + q] = f2bf(f1[q]);
            a = __builtin_bit_cast(bf16x8, tt);
        } else {
            usx8 raw = *(const usx8*)(arow + kt * 32);
            if (!l0mode) {
                int col = kt * 32 + quad * 8;
                fx4 s0 = *(const fx4*)&scs[col];
                fx4 s1 = *(const fx4*)&scs[col + 4];
                fx4 h0 = *(const fx4*)&shs[col];
                fx4 h1 = *(const fx4*)&shs[col + 4];
                usx8 tt;
#pragma unroll
                for (int q = 0; q < 4; q++)
                    tt[q] = f2bf(fmaxf(s0[q] * bf2f(raw[q]) + h0[q], 0.f));
#pragma unroll
                for (int q = 0; q < 4; q++)
                    tt[4 + q] = f2bf(fmaxf(s1[q] * bf2f(raw[4 + q]) + h1[q], 0.f));
                a = __builtin_bit_cast(bf16x8, tt);
            } else {
                a = __builtin_bit_cast(bf16x8, raw);
            }
        }
        const unsigned short* wf = Wf + ((size_t)(kt * 8) * 64 + lane) * 8;
#pragma unroll
        for (int nt = 0; nt < 8; nt++) {
            bf16x8 bfr = __builtin_bit_cast(bf16x8, *(const usx8*)(wf + (size_t)nt * 64 * 8));
            acc[nt] = __builtin_amdgcn_mfma_f32_16x16x32_bf16(a, bfr, acc[nt], 0, 0, 0);
        }
    }
    float dsc[4];
#pragma unroll
    for (int r = 0; r < 4; r++) dsc[r] = dis[m0 + quad * 4 + r];
    // transpose through per-wave LDS region (stride 136 shorts, 16B-aligned rows)
    unsigned short* lw = ldsC + wv * 16 * 136;
#pragma unroll
    for (int nt = 0; nt < 8; nt++) {
        int col = nt * 16 + row;
#pragma unroll
        for (int r = 0; r < 4; r++) {
            lw[(quad * 4 + r) * 136 + col] = f2bf(acc[nt][r] * dsc[r]);
        }
    }
    // no __syncthreads needed: same-wave LDS RAW handled by lgkmcnt
    int row16 = lane >> 2;
    int seg = lane & 3;
    const unsigned short* src = lw + row16 * 136 + seg * 32;
    unsigned short* dst = C + (size_t)(m0 + row16) * HDIM + seg * 32;
#pragma unroll
    for (int k = 0; k < 4; k++) {
        *(usx8*)(dst + k * 8) = *(const usx8*)(src + k * 8);
    }
}

// ---------------- aggregation (persistent) + fused BN col-stats ----------------
__global__ __launch_bounds__(256) void aggregate(const unsigned short* __restrict__ hw,
                                                 const float* __restrict__ dis,
                                                 const int* __restrict__ offs,
                                                 const int* __restrict__ cnt,
                                                 const int* __restrict__ csrc,
                                                 const unsigned short* __restrict__ bias,
                                                 unsigned short* __restrict__ agg,
                                                 float* __restrict__ gsum8, int n) {
    __shared__ float red[16 * 128];
    int t = threadIdx.x;
    int lane = t & 63;
    int wv = t >> 6;
    int grp = lane >> 4, sub = lane & 15;
    int colb = sub * 8;
    usx8 bv = *(const usx8*)(bias + colb);
    float csum[8], csq[8];
#pragma unroll
    for (int q = 0; q < 8; q++) {
        csum[q] = 0.f;
        csq[q] = 0.f;
    }
    int stride = gridDim.x * 16;
    for (int node = blockIdx.x * 16 + wv * 4 + grp; node < n; node += stride) {
        usx8 sv = *(const usx8*)(hw + (size_t)node * HDIM + colb);
        float a[8];
#pragma unroll
        for (int q = 0; q < 8; q++) a[q] = bf2f(sv[q]);
        int o = offs[node], c = cnt[node];
        int s0 = (c > 0) ? csrc[o] : 0;
        int s1 = (c > 1) ? csrc[o + 1] : 0;
        int s2 = (c > 2) ? csrc[o + 2] : 0;
        int s3 = (c > 3) ? csrc[o + 3] : 0;
        int j = 0;
        while (j < c) {
            usx8 v0 = *(const usx8*)(hw + (size_t)s0 * HDIM + colb);
            usx8 v1 = *(const usx8*)(hw + (size_t)s1 * HDIM + colb);
            usx8 v2 = *(const usx8*)(hw + (size_t)s2 * HDIM + colb);
            usx8 v3 = *(const usx8*)(hw + (size_t)s3 * HDIM + colb);
            s0 = (j + 4 < c) ? csrc[o + j + 4] : 0;
            s1 = (j + 5 < c) ? csrc[o + j + 5] : 0;
            s2 = (j + 6 < c) ? csrc[o + j + 6] : 0;
            s3 = (j + 7 < c) ? csrc[o + j + 7] : 0;
#pragma unroll
            for (int q = 0; q < 8; q++) a[q] += bf2f(v0[q]);
            if (j + 1 < c) {
#pragma unroll
                for (int q = 0; q < 8; q++) a[q] += bf2f(v1[q]);
            }
            if (j + 2 < c) {
#pragma unroll
                for (int q = 0; q < 8; q++) a[q] += bf2f(v2[q]);
            }
            if (j + 3 < c) {
#pragma unroll
                for (int q = 0; q < 8; q++) a[q] += bf2f(v3[q]);
            }
            j += 4;
        }
        float di = dis[node];
        usx8 ov;
#pragma unroll
        for (int q = 0; q < 8; q++) {
            float val = bf2f(bv[q]) + di * a[q];
            ov[q] = f2bf(val);
            float vr = bf2f(ov[q]);  // stats on stored bf16 value (matches col_stats)
            csum[q] += vr;
            csq[q] += vr * vr;
        }
        *(usx8*)(agg + (size_t)node * HDIM + colb) = ov;
    }
    int gidx = wv * 4 + grp;
    int rep = (blockIdx.x & 7) * 256;
    // reduce sums
#pragma unroll
    for (int q = 0; q < 8; q++) red[gidx * 128 + colb + q] = csum[q];
    __syncthreads();
    if (t < 128) {
        float s = 0.f;
#pragma unroll
        for (int g = 0; g < 16; g++) s += red[g * 128 + t];
        atomicAdd(&gsum8[rep + t], s);
    }
    __syncthreads();
#pragma unroll
    for (int q = 0; q < 8; q++) red[gidx * 128 + colb + q] = csq[q];
    __syncthreads();
    if (t < 128) {
        float s = 0.f;
#pragma unroll
        for (int g = 0; g < 16; g++) s += red[g * 128 + t];
        atomicAdd(&gsum8[rep + 128 + t], s);
    }
}

// ---------------- pooling (computes BN3 in-block, fused ReLU) ----------------
__global__ void pool(const unsigned short* __restrict__ hin, const int* __restrict__ goff,
                     const int* __restrict__ gcnt, const float* __restrict__ gsum3,
                     const unsigned short* __restrict__ gamma,
                     const unsigned short* __restrict__ beta, float* __restrict__ pooled,
                     float invn) {
    __shared__ float scs[128], shs[128];
    __shared__ float ls[256];
    int g = blockIdx.x, t = threadIdx.x;
    if (t < 128) {
        float s = 0.f, s2 = 0.f;
#pragma unroll
        for (int r = 0; r < 8; r++) {
            s += gsum3[r * 256 + t];
            s2 += gsum3[r * 256 + 128 + t];
        }
        float m = s * invn;
        float vv = s2 * invn - m * m;
        float sc = bf2f(gamma[t]) * rsqrtf(vv + 1e-5f);
        scs[t] = sc;
        shs[t] = bf2f(beta[t]) - m * sc;
    }
    __syncthreads();
    int c = t & 127, p = t >> 7;
    float scale = scs[c], shift = shs[c];
    int s = goff[g], cn = gcnt[g];
    float acc = 0.f;
    for (int r = s + p; r < s + cn; r += 2)
        acc += fmaxf(scale * bf2f(hin[(size_t)r * HDIM + c]) + shift, 0.f);
    ls[t] = acc;
    __syncthreads();
    if (t < 128) pooled[(size_t)g * HDIM + t] = (ls[t] + ls[t + 128]) / fmaxf((float)cn, 1.f);
}
__global__ void pooled_bn(const float* __restrict__ pooled, const unsigned short* __restrict__ g,
                          const unsigned short* __restrict__ be, float* __restrict__ psc,
                          float* __restrict__ psh, int G_) {
    int t = threadIdx.x;
    int c = t & 127, p = t >> 7;
    float s = 0.f, s2 = 0.f;
    for (int r = p; r < G_; r += 4) {
        float v = pooled[(size_t)r * HDIM + c];
        s += v;
        s2 += v * v;
    }
    __shared__ float ls[512], ls2[512];
    ls[t] = s;
    ls2[t] = s2;
    __syncthreads();
    if (t < 128) {
        float S = ls[t] + ls[t + 128] + ls[t + 256] + ls[t + 384];
        float S2 = ls2[t] + ls2[t + 128] + ls2[t + 256] + ls2[t + 384];
        float m = S / (float)G_;
        float v = S2 / (float)G_ - m * m;
        float sc = bf2f(g[t]) * rsqrtf(v + 1e-5f);
        psc[t] = sc;
        psh[t] = bf2f(be[t]) - m * sc;
    }
}
// ---------------- fused MLP head + log_softmax ----------------
__global__ void mlp12(const float* __restrict__ pooled, const float* __restrict__ psc,
                      const float* __restrict__ psh, const unsigned short* __restrict__ lw1,
                      const unsigned short* __restrict__ lb1,
                      const unsigned short* __restrict__ lw2,
                      const unsigned short* __restrict__ lb2, void* __restrict__ out,
                      const int* __restrict__ flags) {
    int r = blockIdx.x, t = threadIdx.x;
    __shared__ float row[128];
    __shared__ float z1s[128];
    __shared__ float z2[10];
    __shared__ float lse;
    row[t] = psc[t] * pooled[(size_t)r * HDIM + t] + psh[t];
    __syncthreads();
    float acc = bf2f(lb1[t]);
    for (int k = 0; k < 128; k++) acc += row[k] * bf2f(lw1[k * HDIM + t]);
    z1s[t] = fmaxf(acc, 0.f);
    __syncthreads();
    if (t < 10) {
        float a = bf2f(lb2[t]);
        for (int k = 0; k < 128; k++) a += z1s[k] * bf2f(lw2[k * 10 + t]);
        z2[t] = a;
    }
    __syncthreads();
    if (t == 0) {
        float m = z2[0];
        for (int j = 1; j < 10; j++) m = fmaxf(m, z2[j]);
        float s = 0.f;
        for (int j = 0; j < 10; j++) s += expf(z2[j] - m);
        lse = m + logf(s);
    }
    __syncthreads();
    if (t < 10) {
        float v = z2[t] - lse;
        if (flags[0]) ((unsigned short*)out)[r * 10 + t] = f2bf(v);
        else ((float*)out)[r * 10 + t] = v;
    }
}

extern "C" void kernel_launch(void* const* d_in, const int* in_sizes, int n_in,
                              void* d_out, int out_size, void* d_ws, size_t ws_size,
                              hipStream_t stream) {
    const void* x = d_in[0];
    const void* ei = d_in[1];
    const void* batch = d_in[2];

    int N_ = in_sizes[2];
    int E_ = in_sizes[1] / 2;
    int G_ = out_size / 10;

    const int TILE = 4096;  // ntiles <= 512 required by s1_scan (E<=2M)
    int NB = (N_ + 511) / 512;  // <=256 required by in-kernel base scans
    int ntiles = (E_ + TILE - 1) / TILE;
    int L = NB * ntiles;

    char* ws = (char*)d_ws;
    auto alloc = [&](size_t bytes) -> char* {
        char* p = ws;
        ws += (bytes + 255) & ~(size_t)255;
        return p;
    };
    int* flags = (int*)alloc(256);
    float* dis = (float*)alloc((size_t)N_ * 4);
    int* offs = (int*)alloc((size_t)N_ * 4);
    int* cnt = (int*)alloc((size_t)N_ * 4);
    int* Ct = (int*)alloc((size_t)L * 4);
    int* btot = (int*)alloc(1024);
    unsigned int* pairs = (unsigned int*)alloc((size_t)E_ * 4);
    int* csrc = (int*)alloc((size_t)E_ * 4);
    unsigned short* hw = (unsigned short*)alloc((size_t)N_ * HDIM * 2);
    unsigned short* aggbuf = (unsigned short*)alloc((size_t)N_ * HDIM * 2);
    unsigned short* wconv = (unsigned short*)alloc(70000 * 2);
    unsigned short* wfrag = (unsigned short*)alloc(3 * HDIM * HDIM * 2);
    float* gsumAll = (float*)alloc(6144 * 4);  // 3 layers x 8 replicas x (128 sum + 128 sq)
    int* gcnt = (int*)alloc((size_t)G_ * 4);
    int* goff = (int*)alloc((size_t)G_ * 4);
    float* pooled = (float*)alloc((size_t)G_ * HDIM * 4);
    float* psc = (float*)alloc(128 * 4);
    float* psh = (float*)alloc(128 * 4);

    // wconv layout (element offsets)
    const int oB = 49152;
    const int oLB1 = oB + 1408;
    const int oLW1 = oLB1 + 128;
    const int oLW2 = oLW1 + 16384;
    const int oLB2 = oLW2 + 1280;

    ParamTab tab;
    const int srcIdx[15] = {4, 5, 6, 8, 9, 10, 12, 13, 14, 15, 16, 18, 17, 19, 20};
    const int dstOff[15] = {oB + 0, oB + 128, oB + 256,
                            oB + 384, oB + 512, oB + 640,
                            oB + 768, oB + 896, oB + 1024,
                            oB + 1152, oB + 1280,
                            oLB1, oLW1, oLW2, oLB2};
    for (int i = 0; i < 15; i++) {
        tab.p[i] = d_in[srcIdx[i]];
        tab.n[i] = in_sizes[srcIdx[i]];
        tab.off[i] = dstOff[i];
    }

    int p1_grid = ntiles + 15 + 2 + 24 + 1;
    phase1<<<p1_grid, 256, 0, stream>>>((const unsigned int*)x, (const unsigned int*)ei, ei,
                                        batch, d_in[3], d_in[7], d_in[11], tab, flags, gsumAll,
                                        Ct, wconv, wfrag, goff, gcnt, E_, N_, G_, NB, ntiles,
                                        TILE);
    s1_scan<<<NB, 512, 0, stream>>>(Ct, btot, NB, ntiles);
    p1_scatter<<<ntiles, 256, 0, stream>>>(ei, flags, Ct, btot, pairs, E_, NB, ntiles, TILE);
    p2_build<<<NB, 256, 0, stream>>>(pairs, btot, csrc, offs, cnt, dis, E_, N_, NB);

    int mm_blocks = (((N_ + 15) / 16) * 64 + 255) / 256;
    float invn = 1.f / (float)N_;

    for (int l = 0; l < 3; l++) {
        const void* A = (l == 0) ? x : (const void*)aggbuf;
        const float* gp = (l == 0) ? nullptr : (gsumAll + (size_t)(l - 1) * 2048);
        const unsigned short* gam = wconv + oB + (l ? (l - 1) * 384 + 128 : 0);
        const unsigned short* bet = wconv + oB + (l ? (l - 1) * 384 + 256 : 0);
        mm_mfma<<<mm_blocks, 256, 0, stream>>>(A, wfrag + (size_t)l * HDIM * HDIM, hw, N_, gp,
                                               gam, bet, dis, flags, (l == 0) ? 1 : 0, invn);
        aggregate<<<768, 256, 0, stream>>>(hw, dis, offs, cnt, csrc, wconv + oB + l * 384,
                                           aggbuf, gsumAll + (size_t)l * 2048, N_);
    }

    pool<<<G_, 256, 0, stream>>>(aggbuf, goff, gcnt, gsumAll + 2 * 2048,
                                 wconv + oB + 2 * 384 + 128, wconv + oB + 2 * 384 + 256, pooled,
                                 invn);
    pooled_bn<<<1, 512, 0, stream>>>(pooled, wconv + oB + 1152, wconv + oB + 1280, psc, psh, G_);
    mlp12<<<G_, 128, 0, stream>>>(pooled, psc, psh, wconv + oLW1, wconv + oLB1, wconv + oLW2,
                                  wconv + oLB2, d_out, flags);
}